// Round 9
// baseline (411.083 us; speedup 1.0000x reference)
//
#include <hip/hip_runtime.h>
#include <stdint.h>
#include <stddef.h>

// ---------------- problem constants ----------------
#define T_TOK  8192        // B*S tokens
#define DIMK   1024        // model dim
#define INTERK 1024        // routed expert inter dim
#define NEXP   8
#define SINT   2048        // shared inter dim
#define CAP    18432       // 2*T + 8*256 padding capacity (slot rows, 256-aligned)
#define RT256  72          // CAP/256 row tiles (worst case)

typedef float  f32x4  __attribute__((ext_vector_type(4)));
typedef short  bf16x8 __attribute__((ext_vector_type(8)));

typedef __attribute__((address_space(1))) const unsigned int gas_u32;
typedef __attribute__((address_space(3))) unsigned int las_u32;

__device__ __forceinline__ void gload16(const void* g, void* l) {
  __builtin_amdgcn_global_load_lds((gas_u32*)g, (las_u32*)l, 16, 0, 0);
}

__device__ __forceinline__ unsigned short f2b(float f) {   // f32 -> bf16 RNE
  unsigned int u = __float_as_uint(f);
  u = (u + 0x7FFFu + ((u >> 16) & 1u)) >> 16;
  return (unsigned short)u;
}
__device__ __forceinline__ float b2f(unsigned short h) {
  return __uint_as_float(((unsigned int)h) << 16);
}

// raw barrier with compile-time memory fences (no vmcnt/lgkmcnt drain)
__device__ __forceinline__ void barrier_nodrain() {
  asm volatile("" ::: "memory");
  __builtin_amdgcn_s_barrier();
  asm volatile("" ::: "memory");
}

// ---------------- f32 -> bf16 convert (plain) ----------------
__global__ __launch_bounds__(256) void cvt_kernel(const float4* __restrict__ in,
                                                  unsigned short* __restrict__ out, int n4) {
  int i = blockIdx.x * 256 + threadIdx.x;
  if (i >= n4) return;
  float4 v = in[i];
  ushort4 o;
  o.x = f2b(v.x); o.y = f2b(v.y); o.z = f2b(v.z); o.w = f2b(v.w);
  *reinterpret_cast<ushort4*>(&out[(size_t)i * 4]) = o;
}

// ---------------- f32 -> bf16 convert, interleaving w1/w3 rows in 16-row groups ----
template <int ROWS_PER_E, int K4>
__global__ __launch_bounds__(256) void cvt_w13_kernel(
    const float4* __restrict__ w1, const float4* __restrict__ w3,
    unsigned short* __restrict__ out, int n /* = E*ROWS_PER_E*K4 */) {
  int idx = blockIdx.x * 256 + threadIdx.x;
  int is3 = idx >= n;
  int i = is3 ? idx - n : idx;
  if (i >= n) return;
  int r  = i / K4;
  int kc = i - r * K4;
  int e  = r / ROWS_PER_E;
  int rr = r - e * ROWS_PER_E;
  int g  = rr >> 4;
  size_t dst_r = (size_t)e * (2 * ROWS_PER_E) + g * 32 + (is3 ? 16 : 0) + (rr & 15);
  float4 v = (is3 ? w3 : w1)[i];
  ushort4 o;
  o.x = f2b(v.x); o.y = f2b(v.y); o.z = f2b(v.z); o.w = f2b(v.w);
  *reinterpret_cast<ushort4*>(&out[(dst_r * K4 + kc) * 4]) = o;
}

// ---------------- gate: f32 logits, softmax, top-2 (no atomics) ----------------
__global__ __launch_bounds__(256) void gate_kernel(
    const float* __restrict__ x, const float* __restrict__ gw, const float* __restrict__ gb,
    int* __restrict__ top_i, float* __restrict__ top_w) {
  int t    = blockIdx.x * 4 + (threadIdx.x >> 6);
  int lane = threadIdx.x & 63;
  const float* xr = x + (size_t)t * DIMK;
  float acc[NEXP];
#pragma unroll
  for (int e = 0; e < NEXP; ++e) acc[e] = 0.f;
  for (int i = lane; i < DIMK; i += 64) {
    float xv = xr[i];
#pragma unroll
    for (int e = 0; e < NEXP; ++e) acc[e] += xv * gw[e * DIMK + i];
  }
#pragma unroll
  for (int e = 0; e < NEXP; ++e) {
    float v = acc[e];
#pragma unroll
    for (int off = 32; off > 0; off >>= 1) v += __shfl_down(v, off, 64);
    acc[e] = v;
  }
  if (lane == 0) {
    float lg[NEXP];
#pragma unroll
    for (int e = 0; e < NEXP; ++e) lg[e] = acc[e] + gb[e];
    int i0 = 0;
#pragma unroll
    for (int e = 1; e < NEXP; ++e) if (lg[e] > lg[i0]) i0 = e;   // first index wins ties
    int i1 = (i0 == 0) ? 1 : 0;
#pragma unroll
    for (int e = 0; e < NEXP; ++e) if (e != i0 && lg[e] > lg[i1]) i1 = e;
    float mx = lg[i0], s = 0.f;
#pragma unroll
    for (int e = 0; e < NEXP; ++e) s += expf(lg[e] - mx);
    top_i[t * 2]     = i0;
    top_i[t * 2 + 1] = i1;
    top_w[t * 2]     = expf(lg[i0] - mx) / s;
    top_w[t * 2 + 1] = expf(lg[i1] - mx) / s;
  }
}

// ---------------- route_build: count + scan + slot-assign, deterministic ----------
__global__ __launch_bounds__(512) void route_build_kernel(
    const int* __restrict__ top_i, int* __restrict__ order, int* __restrict__ pos,
    int* __restrict__ poff_g) {
  __shared__ int cnt[NEXP][512];
  __shared__ int base[NEXP][512];
  __shared__ int totals[NEXP];
  __shared__ int poff_s[NEXP + 1];
  int tid = threadIdx.x;
  int lane = tid & 63, w = tid >> 6;
  const int t0 = tid * 16;

  int c[NEXP];
#pragma unroll
  for (int e = 0; e < NEXP; ++e) c[e] = 0;
  for (int j = 0; j < 16; ++j) {
    int e0 = top_i[(t0 + j) * 2];
    int e1 = top_i[(t0 + j) * 2 + 1];
#pragma unroll
    for (int e = 0; e < NEXP; ++e) c[e] += (e0 == e) + (e1 == e);
  }
#pragma unroll
  for (int e = 0; e < NEXP; ++e) cnt[e][tid] = c[e];
  __syncthreads();

  {
    int running = 0;
    for (int ch = 0; ch < 8; ++ch) {
      int v = cnt[w][ch * 64 + lane];
      int incl = v;
#pragma unroll
      for (int off = 1; off < 64; off <<= 1) {
        int u = __shfl_up(incl, off, 64);
        if (lane >= off) incl += u;
      }
      base[w][ch * 64 + lane] = running + incl - v;
      running += __shfl(incl, 63, 64);
    }
    if (lane == 0) totals[w] = running;
  }
  __syncthreads();

  if (tid == 0) {
    int off = 0;
#pragma unroll
    for (int e = 0; e < NEXP; ++e) {
      poff_s[e] = off;
      off += (totals[e] + 255) & ~255;
    }
    poff_s[NEXP] = off;
#pragma unroll
    for (int e = 0; e <= NEXP; ++e) poff_g[e] = poff_s[e];
  }
  __syncthreads();

  int cur[NEXP];
#pragma unroll
  for (int e = 0; e < NEXP; ++e) cur[e] = poff_s[e] + base[e][tid];
  for (int j = 0; j < 16; ++j) {
    int t = t0 + j;
#pragma unroll
    for (int k = 0; k < 2; ++k) {
      int ei = top_i[t * 2 + k];
      int p = 0;
#pragma unroll
      for (int e = 0; e < NEXP; ++e)
        if (ei == e) { p = cur[e]; cur[e] = p + 1; }
      order[p]       = t;
      pos[t * 2 + k] = p;
    }
  }

#pragma unroll
  for (int e = 0; e < NEXP; ++e) {
    int s = poff_s[e] + totals[e], en = poff_s[e + 1];
    for (int i = s + tid; i < en; i += 512) order[i] = 0;
  }
}

// ---------------- pipelined GEMM: BM=256, BN=128, BK=64, 512 thr (8 waves 4x2) ----
// Depth-2 prefetch, 3 LDS buffers (144 KB), counted vmcnt(6), fine 2-phase interleave:
// per K-tile: {ds B8+A4 | stage 3 | bar | lgkm0 | 16 MFMA | bar} x2 (A m-pairs).
// B-fragments held in registers across both phases. Raw barriers, no mid-loop drain.
// Grid: blockIdx.x = N-slice (fast-varying -> L2 A-row sharing), blockIdx.y = M tile.
// EPI 0: paired swiglu epilogue (interleaved w1/w3 B) -> bf16 H, real cols = BN/2
// EPI 1: bias -> bf16 out;  EPI 2: bias -> f32 out
#define A_ELE   16384   // 256*64 elements per A buffer
#define B_ELE   8192    // 128*64 elements per B buffer
#define BUF_ELE (A_ELE + B_ELE)
template <bool EXPERTS, bool GATHER, int EPI>
__global__ __launch_bounds__(512) void gemm256_kernel(
    const unsigned short* __restrict__ A, int lda,
    const int* __restrict__ order, const int* __restrict__ poff,
    const unsigned short* __restrict__ B,          // row-major [N][K], per-expert wstride
    const float* __restrict__ bias1, const float* __restrict__ bias3,
    size_t wstride, int bstride, int K,
    void* __restrict__ outp, int ldo) {
  __shared__ unsigned short lds[3 * BUF_ELE];   // 144 KiB

  int rowbase = blockIdx.y * 256;
  int expert  = 0;
  if (EXPERTS) {
    if (rowbase >= poff[NEXP]) return;
    while (expert < NEXP - 1 && rowbase >= poff[expert + 1]) ++expert;
  }
  const unsigned short* Be = B + (size_t)expert * wstride;

  int tid = threadIdx.x;
  int lane = tid & 63, wid = tid >> 6;
  int wr = wid >> 1, wc = wid & 1;            // 4 x 2 wave grid: 64 rows x 64 cols each
  int ncolbase = blockIdx.x * 128;

  // staging addresses (element offsets); source chunk pre-swizzled: sub = (g&7)^(row&7)
  size_t aoff[4], boff[2];
#pragma unroll
  for (int l = 0; l < 4; ++l) {
    int g = l * 512 + tid;
    int r = g >> 3;
    int sub = (g & 7) ^ (r & 7);
    int gr = GATHER ? order[rowbase + r] : (rowbase + r);
    aoff[l] = (size_t)gr * lda + (size_t)(sub * 8);
  }
#pragma unroll
  for (int l = 0; l < 2; ++l) {
    int g = l * 512 + tid;
    int r = g >> 3;
    int sub = (g & 7) ^ (r & 7);
    boff[l] = (size_t)(ncolbase + r) * K + (size_t)(sub * 8);
  }

  f32x4 acc[4][4];
#pragma unroll
  for (int m = 0; m < 4; ++m)
#pragma unroll
    for (int n = 0; n < 4; ++n) acc[m][n] = f32x4{0.f, 0.f, 0.f, 0.f};

  const int NT = K >> 6;

  // ---- prologue: stage tiles 0 and 1 (6 loads/thread each) ----
#pragma unroll
  for (int l = 0; l < 4; ++l)
    gload16(A + aoff[l], &lds[(size_t)(l * 512 + tid) * 8]);
#pragma unroll
  for (int l = 0; l < 2; ++l)
    gload16(Be + boff[l], &lds[A_ELE + (size_t)(l * 512 + tid) * 8]);
#pragma unroll
  for (int l = 0; l < 4; ++l)
    gload16(A + aoff[l] + 64, &lds[BUF_ELE + (size_t)(l * 512 + tid) * 8]);
#pragma unroll
  for (int l = 0; l < 2; ++l)
    gload16(Be + boff[l] + 64, &lds[BUF_ELE + A_ELE + (size_t)(l * 512 + tid) * 8]);

  unsigned int off_r = 0, off_m = BUF_ELE, off_w = 2 * BUF_ELE;

  for (int t = 0; t < NT; ++t) {
    // wait: tile t landed (tile t+1's 6 loads may stay in flight)
    if (t + 1 < NT) {
      asm volatile("s_waitcnt vmcnt(6)" ::: "memory");
    } else {
      asm volatile("s_waitcnt vmcnt(0)" ::: "memory");
    }
    barrier_nodrain();   // B1: tile t visible to all; buf[off_w] free of readers

    const unsigned short* Ab = &lds[off_r];
    const unsigned short* Bb = &lds[off_r + A_ELE];
    const bool stage = (t + 2 < NT);
    const int kb = (t + 2) << 6;

    // ===== phase 0: ds B(8)+A m0,m1(4) | stage 3 A-loads | bar | 16 MFMA =====
    bf16x8 bfr[4][2];
#pragma unroll
    for (int n = 0; n < 4; ++n) {
      int rb = wc * 64 + n * 16 + (lane & 15);
#pragma unroll
      for (int kk = 0; kk < 2; ++kk) {
        int sb = (kk * 4 + (lane >> 4)) ^ (rb & 7);
        bfr[n][kk] = *(const bf16x8*)&Bb[rb * 64 + sb * 8];
      }
    }
    bf16x8 a0[2][2];
#pragma unroll
    for (int m = 0; m < 2; ++m) {
      int ra = wr * 64 + m * 16 + (lane & 15);
#pragma unroll
      for (int kk = 0; kk < 2; ++kk) {
        int sa = (kk * 4 + (lane >> 4)) ^ (ra & 7);
        a0[m][kk] = *(const bf16x8*)&Ab[ra * 64 + sa * 8];
      }
    }
    if (stage) {
#pragma unroll
      for (int l = 0; l < 3; ++l)
        gload16(A + aoff[l] + kb, &lds[off_w + (size_t)(l * 512 + tid) * 8]);
    }
    barrier_nodrain();   // B2: issue burst done CU-wide
    asm volatile("s_waitcnt lgkmcnt(0)" ::: "memory");
    __builtin_amdgcn_sched_barrier(0);
    __builtin_amdgcn_s_setprio(1);
#pragma unroll
    for (int m = 0; m < 2; ++m)
#pragma unroll
      for (int n = 0; n < 4; ++n)
#pragma unroll
        for (int kk = 0; kk < 2; ++kk)
          acc[m][n] = __builtin_amdgcn_mfma_f32_16x16x32_bf16(a0[m][kk], bfr[n][kk], acc[m][n], 0, 0, 0);
    __builtin_amdgcn_s_setprio(0);
    barrier_nodrain();   // B3

    // ===== phase 1: ds A m2,m3(4) | stage 3 (A+B) | bar | 16 MFMA =====
    bf16x8 a1[2][2];
#pragma unroll
    for (int m = 0; m < 2; ++m) {
      int ra = wr * 64 + (m + 2) * 16 + (lane & 15);
#pragma unroll
      for (int kk = 0; kk < 2; ++kk) {
        int sa = (kk * 4 + (lane >> 4)) ^ (ra & 7);
        a1[m][kk] = *(const bf16x8*)&Ab[ra * 64 + sa * 8];
      }
    }
    if (stage) {
      gload16(A + aoff[3] + kb, &lds[off_w + (size_t)(3 * 512 + tid) * 8]);
#pragma unroll
      for (int l = 0; l < 2; ++l)
        gload16(Be + boff[l] + kb, &lds[off_w + A_ELE + (size_t)(l * 512 + tid) * 8]);
    }
    barrier_nodrain();   // B4
    asm volatile("s_waitcnt lgkmcnt(0)" ::: "memory");
    __builtin_amdgcn_sched_barrier(0);
    __builtin_amdgcn_s_setprio(1);
#pragma unroll
    for (int m = 0; m < 2; ++m)
#pragma unroll
      for (int n = 0; n < 4; ++n)
#pragma unroll
        for (int kk = 0; kk < 2; ++kk)
          acc[m + 2][n] = __builtin_amdgcn_mfma_f32_16x16x32_bf16(a1[m][kk], bfr[n][kk], acc[m + 2][n], 0, 0, 0);
    __builtin_amdgcn_s_setprio(0);
    // next tile's B1 barrier protects buf rotation (all reads of buf r done: lgkm0 above)

    // rotate buffers: r <- m <- w <- r
    unsigned int tmp = off_r; off_r = off_m; off_m = off_w; off_w = tmp;
  }

  if (EPI == 0) {
    // interleaved pairs: n even = w1 fragment, n odd = w3 fragment; real cols = BN/2
#pragma unroll
    for (int m = 0; m < 4; ++m)
#pragma unroll
      for (int np = 0; np < 2; ++np) {
        int realcol = (ncolbase >> 1) + wc * 32 + np * 16 + (lane & 15);
        float bb1 = bias1[bstride * expert + realcol];
        float bb3 = bias3[bstride * expert + realcol];
#pragma unroll
        for (int j = 0; j < 4; ++j) {
          int row  = rowbase + wr * 64 + m * 16 + (lane >> 4) * 4 + j;
          float a1 = acc[m][2 * np][j] + bb1;
          float a3 = acc[m][2 * np + 1][j] + bb3;
          float hv = (a1 / (1.f + __expf(-a1))) * a3;   // silu(a1)*a3
          ((unsigned short*)outp)[(size_t)row * ldo + realcol] = f2b(hv);
        }
      }
  } else {
#pragma unroll
    for (int m = 0; m < 4; ++m)
#pragma unroll
      for (int n = 0; n < 4; ++n) {
        int col  = ncolbase + wc * 64 + n * 16 + (lane & 15);
        float bb = bias1[bstride * expert + col];
#pragma unroll
        for (int j = 0; j < 4; ++j) {
          int row = rowbase + wr * 64 + m * 16 + (lane >> 4) * 4 + j;
          float v = acc[m][n][j] + bb;
          if (EPI == 2)
            ((float*)outp)[(size_t)row * ldo + col] = v;
          else
            ((unsigned short*)outp)[(size_t)row * ldo + col] = f2b(v);
        }
      }
  }
}

// ---------------- combine: out += w0*y[p0] + w1*y[p1] ----------------
__global__ __launch_bounds__(256) void combine_kernel(
    float* __restrict__ out, const unsigned short* __restrict__ y,
    const int* __restrict__ pos, const float* __restrict__ tw) {
  size_t idx = (size_t)blockIdx.x * 256 + threadIdx.x;
  if (idx >= (size_t)T_TOK * DIMK) return;
  int t = (int)(idx >> 10);
  int d = (int)(idx & 1023);
  int p0 = pos[t * 2], p1 = pos[t * 2 + 1];
  float w0 = tw[t * 2], w1 = tw[t * 2 + 1];
  out[idx] += w0 * b2f(y[(size_t)p0 * DIMK + d]) + w1 * b2f(y[(size_t)p1 * DIMK + d]);
}

// ---------------- launch ----------------
extern "C" void kernel_launch(void* const* d_in, const int* in_sizes, int n_in,
                              void* d_out, int out_size, void* d_ws, size_t ws_size,
                              hipStream_t stream) {
  const float* x   = (const float*)d_in[0];
  const float* gw  = (const float*)d_in[1];
  const float* gb  = (const float*)d_in[2];
  const float* w1  = (const float*)d_in[3];
  const float* b1  = (const float*)d_in[4];
  const float* w3  = (const float*)d_in[5];
  const float* b3  = (const float*)d_in[6];
  const float* w2  = (const float*)d_in[7];
  const float* b2  = (const float*)d_in[8];
  const float* ws1 = (const float*)d_in[9];
  const float* bs1 = (const float*)d_in[10];
  const float* ws3 = (const float*)d_in[11];
  const float* bs3 = (const float*)d_in[12];
  const float* ws2 = (const float*)d_in[13];
  const float* bs2 = (const float*)d_in[14];
  float* out = (float*)d_out;
  (void)in_sizes; (void)n_in; (void)out_size; (void)ws_size;

  char* p = (char*)d_ws;
  auto alloc = [&](size_t bytes) -> void* {
    void* r = (void*)p;
    p += (bytes + 255) & ~(size_t)255;
    return r;
  };
  unsigned short* xb    = (unsigned short*)alloc((size_t)T_TOK * DIMK * 2);
  unsigned short* w13r  = (unsigned short*)alloc((size_t)NEXP * 2 * INTERK * DIMK * 2);
  unsigned short* w2b   = (unsigned short*)alloc((size_t)NEXP * DIMK * INTERK * 2);
  unsigned short* w13s  = (unsigned short*)alloc((size_t)2 * SINT * DIMK * 2);
  unsigned short* ws2b  = (unsigned short*)alloc((size_t)DIMK * SINT * 2);
  unsigned short* h     = (unsigned short*)alloc((size_t)CAP * INTERK * 2);
  unsigned short* yb    = (unsigned short*)alloc((size_t)CAP * DIMK * 2);
  unsigned short* hs    = (unsigned short*)alloc((size_t)T_TOK * SINT * 2);
  int*   top_i  = (int*)alloc((size_t)T_TOK * 2 * 4);
  float* top_w  = (float*)alloc((size_t)T_TOK * 2 * 4);
  int*   pos    = (int*)alloc((size_t)T_TOK * 2 * 4);
  int*   order  = (int*)alloc((size_t)CAP * 4);
  int*   poff   = (int*)alloc(64);

  auto cvt = [&](const float* src, unsigned short* dst, size_t n) {
    int n4 = (int)(n / 4);
    cvt_kernel<<<(n4 + 255) / 256, 256, 0, stream>>>((const float4*)src, dst, n4);
  };
  cvt(x,   xb,   (size_t)T_TOK * DIMK);
  cvt(w2,  w2b,  (size_t)NEXP * DIMK * INTERK);
  cvt(ws2, ws2b, (size_t)DIMK * SINT);

  {  // routed w1/w3 -> interleaved w13r
    int n = NEXP * INTERK * (DIMK / 4);
    cvt_w13_kernel<INTERK, DIMK / 4><<<(2 * n + 255) / 256, 256, 0, stream>>>(
        (const float4*)w1, (const float4*)w3, w13r, n);
  }
  {  // shared ws1/ws3 -> interleaved w13s
    int n = SINT * (DIMK / 4);
    cvt_w13_kernel<SINT, DIMK / 4><<<(2 * n + 255) / 256, 256, 0, stream>>>(
        (const float4*)ws1, (const float4*)ws3, w13s, n);
  }

  gate_kernel<<<T_TOK / 4, 256, 0, stream>>>(x, gw, gb, top_i, top_w);
  route_build_kernel<<<1, 512, 0, stream>>>(top_i, order, pos, poff);

  // routed expert pipeline (grid: x = N-slices, y = M row-tiles)
  gemm256_kernel<true, true, 0><<<dim3((2 * INTERK) / 128, RT256), 512, 0, stream>>>(
      xb, DIMK, order, poff, w13r, b1, b3,
      (size_t)2 * INTERK * DIMK, INTERK, DIMK, h, INTERK);
  gemm256_kernel<true, false, 1><<<dim3(DIMK / 128, RT256), 512, 0, stream>>>(
      h, INTERK, (const int*)nullptr, poff, w2b, b2, (const float*)nullptr,
      (size_t)DIMK * INTERK, DIMK, INTERK, (void*)yb, DIMK);

  // shared expert pipeline (writes z straight into d_out)
  gemm256_kernel<false, false, 0><<<dim3((2 * SINT) / 128, T_TOK / 256), 512, 0, stream>>>(
      xb, DIMK, (const int*)nullptr, (const int*)nullptr, w13s, bs1, bs3,
      (size_t)0, 0, DIMK, hs, SINT);
  gemm256_kernel<false, false, 2><<<dim3(DIMK / 128, T_TOK / 256), 512, 0, stream>>>(
      hs, SINT, (const int*)nullptr, (const int*)nullptr, ws2b, bs2, (const float*)nullptr,
      (size_t)0, 0, SINT, (void*)out, DIMK);

  // out += routed combine
  combine_kernel<<<(T_TOK * DIMK) / 256, 256, 0, stream>>>(out, yb, pos, top_w);
}

// Round 10
// 408.726 us; speedup vs baseline: 1.0058x; 1.0058x over previous
//
#include <hip/hip_runtime.h>
#include <stdint.h>
#include <stddef.h>

// ---------------- problem constants ----------------
#define T_TOK  8192        // B*S tokens
#define DIMK   1024        // model dim
#define INTERK 1024        // routed expert inter dim
#define NEXP   8
#define SINT   2048        // shared inter dim
#define CAP    18432       // 2*T + 8*256 padding capacity (slot rows, 256-aligned)
#define RT256  72          // CAP/256 row tiles (worst case)

typedef float  f32x4  __attribute__((ext_vector_type(4)));
typedef short  bf16x8 __attribute__((ext_vector_type(8)));

typedef __attribute__((address_space(1))) const unsigned int gas_u32;
typedef __attribute__((address_space(3))) unsigned int las_u32;

__device__ __forceinline__ void gload16(const void* g, void* l) {
  __builtin_amdgcn_global_load_lds((gas_u32*)g, (las_u32*)l, 16, 0, 0);
}

__device__ __forceinline__ unsigned short f2b(float f) {   // f32 -> bf16 RNE
  unsigned int u = __float_as_uint(f);
  u = (u + 0x7FFFu + ((u >> 16) & 1u)) >> 16;
  return (unsigned short)u;
}
__device__ __forceinline__ float b2f(unsigned short h) {
  return __uint_as_float(((unsigned int)h) << 16);
}

// raw barrier with compile-time memory fences (no vmcnt/lgkmcnt drain)
__device__ __forceinline__ void barrier_nodrain() {
  asm volatile("" ::: "memory");
  __builtin_amdgcn_s_barrier();
  asm volatile("" ::: "memory");
}

// ---------------- f32 -> bf16 convert (plain) ----------------
__global__ __launch_bounds__(256) void cvt_kernel(const float4* __restrict__ in,
                                                  unsigned short* __restrict__ out, int n4) {
  int i = blockIdx.x * 256 + threadIdx.x;
  if (i >= n4) return;
  float4 v = in[i];
  ushort4 o;
  o.x = f2b(v.x); o.y = f2b(v.y); o.z = f2b(v.z); o.w = f2b(v.w);
  *reinterpret_cast<ushort4*>(&out[(size_t)i * 4]) = o;
}

// ---------------- f32 -> bf16 convert, interleaving w1/w3 rows in 16-row groups ----
template <int ROWS_PER_E, int K4>
__global__ __launch_bounds__(256) void cvt_w13_kernel(
    const float4* __restrict__ w1, const float4* __restrict__ w3,
    unsigned short* __restrict__ out, int n /* = E*ROWS_PER_E*K4 */) {
  int idx = blockIdx.x * 256 + threadIdx.x;
  int is3 = idx >= n;
  int i = is3 ? idx - n : idx;
  if (i >= n) return;
  int r  = i / K4;
  int kc = i - r * K4;
  int e  = r / ROWS_PER_E;
  int rr = r - e * ROWS_PER_E;
  int g  = rr >> 4;
  size_t dst_r = (size_t)e * (2 * ROWS_PER_E) + g * 32 + (is3 ? 16 : 0) + (rr & 15);
  float4 v = (is3 ? w3 : w1)[i];
  ushort4 o;
  o.x = f2b(v.x); o.y = f2b(v.y); o.z = f2b(v.z); o.w = f2b(v.w);
  *reinterpret_cast<ushort4*>(&out[(dst_r * K4 + kc) * 4]) = o;
}

// ---------------- gate: f32 logits, softmax, top-2 (no atomics) ----------------
__global__ __launch_bounds__(256) void gate_kernel(
    const float* __restrict__ x, const float* __restrict__ gw, const float* __restrict__ gb,
    int* __restrict__ top_i, float* __restrict__ top_w) {
  int t    = blockIdx.x * 4 + (threadIdx.x >> 6);
  int lane = threadIdx.x & 63;
  const float* xr = x + (size_t)t * DIMK;
  float acc[NEXP];
#pragma unroll
  for (int e = 0; e < NEXP; ++e) acc[e] = 0.f;
  for (int i = lane; i < DIMK; i += 64) {
    float xv = xr[i];
#pragma unroll
    for (int e = 0; e < NEXP; ++e) acc[e] += xv * gw[e * DIMK + i];
  }
#pragma unroll
  for (int e = 0; e < NEXP; ++e) {
    float v = acc[e];
#pragma unroll
    for (int off = 32; off > 0; off >>= 1) v += __shfl_down(v, off, 64);
    acc[e] = v;
  }
  if (lane == 0) {
    float lg[NEXP];
#pragma unroll
    for (int e = 0; e < NEXP; ++e) lg[e] = acc[e] + gb[e];
    int i0 = 0;
#pragma unroll
    for (int e = 1; e < NEXP; ++e) if (lg[e] > lg[i0]) i0 = e;   // first index wins ties
    int i1 = (i0 == 0) ? 1 : 0;
#pragma unroll
    for (int e = 0; e < NEXP; ++e) if (e != i0 && lg[e] > lg[i1]) i1 = e;
    float mx = lg[i0], s = 0.f;
#pragma unroll
    for (int e = 0; e < NEXP; ++e) s += expf(lg[e] - mx);
    top_i[t * 2]     = i0;
    top_i[t * 2 + 1] = i1;
    top_w[t * 2]     = expf(lg[i0] - mx) / s;
    top_w[t * 2 + 1] = expf(lg[i1] - mx) / s;
  }
}

// ---------------- route_build: count + scan + slot-assign, deterministic ----------
__global__ __launch_bounds__(512) void route_build_kernel(
    const int* __restrict__ top_i, int* __restrict__ order, int* __restrict__ pos,
    int* __restrict__ poff_g) {
  __shared__ int cnt[NEXP][512];
  __shared__ int base[NEXP][512];
  __shared__ int totals[NEXP];
  __shared__ int poff_s[NEXP + 1];
  int tid = threadIdx.x;
  int lane = tid & 63, w = tid >> 6;
  const int t0 = tid * 16;

  int c[NEXP];
#pragma unroll
  for (int e = 0; e < NEXP; ++e) c[e] = 0;
  for (int j = 0; j < 16; ++j) {
    int e0 = top_i[(t0 + j) * 2];
    int e1 = top_i[(t0 + j) * 2 + 1];
#pragma unroll
    for (int e = 0; e < NEXP; ++e) c[e] += (e0 == e) + (e1 == e);
  }
#pragma unroll
  for (int e = 0; e < NEXP; ++e) cnt[e][tid] = c[e];
  __syncthreads();

  {
    int running = 0;
    for (int ch = 0; ch < 8; ++ch) {
      int v = cnt[w][ch * 64 + lane];
      int incl = v;
#pragma unroll
      for (int off = 1; off < 64; off <<= 1) {
        int u = __shfl_up(incl, off, 64);
        if (lane >= off) incl += u;
      }
      base[w][ch * 64 + lane] = running + incl - v;
      running += __shfl(incl, 63, 64);
    }
    if (lane == 0) totals[w] = running;
  }
  __syncthreads();

  if (tid == 0) {
    int off = 0;
#pragma unroll
    for (int e = 0; e < NEXP; ++e) {
      poff_s[e] = off;
      off += (totals[e] + 255) & ~255;
    }
    poff_s[NEXP] = off;
#pragma unroll
    for (int e = 0; e <= NEXP; ++e) poff_g[e] = poff_s[e];
  }
  __syncthreads();

  int cur[NEXP];
#pragma unroll
  for (int e = 0; e < NEXP; ++e) cur[e] = poff_s[e] + base[e][tid];
  for (int j = 0; j < 16; ++j) {
    int t = t0 + j;
#pragma unroll
    for (int k = 0; k < 2; ++k) {
      int ei = top_i[t * 2 + k];
      int p = 0;
#pragma unroll
      for (int e = 0; e < NEXP; ++e)
        if (ei == e) { p = cur[e]; cur[e] = p + 1; }
      order[p]       = t;
      pos[t * 2 + k] = p;
    }
  }

#pragma unroll
  for (int e = 0; e < NEXP; ++e) {
    int s = poff_s[e] + totals[e], en = poff_s[e + 1];
    for (int i = s + tid; i < en; i += 512) order[i] = 0;
  }
}

// ---------------- pipelined GEMM: BM=256, BN={256,128}, BK=32, 512 thr (8 waves) ----
// Depth-2 prefetch, 3 LDS buffers (96/72 KB), counted vmcnt, ONE barrier per K-tile,
// loose round-8-style body (compiler-scheduled waits, no order pins), setprio on MFMA.
// LDS swizzle for 64B rows: chunk ^= (row>>1)&3 (both staging-source and ds_read).
// BN=256: waves 2x4, wave tile 128x64 (0.375 KB LDS-read/MFMA).
// BN=128: waves 4x2, wave tile 64x64, 72 KB LDS -> 2 blocks/CU.
// EPI 0: paired swiglu (interleaved w1/w3 B) -> bf16 H, real cols = BN/2
// EPI 1: bias -> bf16 out;  EPI 2: bias -> f32 out
template <bool EXPERTS, bool GATHER, int EPI, int BN>
__global__ __launch_bounds__(512) void gemm_kernel(
    const unsigned short* __restrict__ A, int lda,
    const int* __restrict__ order, const int* __restrict__ poff,
    const unsigned short* __restrict__ B,          // row-major [N][K], per-expert wstride
    const float* __restrict__ bias1, const float* __restrict__ bias3,
    size_t wstride, int bstride, int K,
    void* __restrict__ outp, int ldo) {
  constexpr int WRsh = (BN == 256) ? 2 : 1;   // wc bits
  constexpr int WTM  = (BN == 256) ? 128 : 64;
  constexpr int MF   = WTM / 16;              // 8 or 4 m-fragments per wave
  constexpr int AE   = 256 * 32;              // A elems per buffer
  constexpr int BE   = BN * 32;
  constexpr int BUF  = AE + BE;
  constexpr int BSW  = BN / 128;              // B staging sweeps (2 or 1)
  __shared__ unsigned short lds[3 * BUF];

  int rowbase = blockIdx.y * 256;
  int expert  = 0;
  if (EXPERTS) {
    if (rowbase >= poff[NEXP]) return;
    while (expert < NEXP - 1 && rowbase >= poff[expert + 1]) ++expert;
  }
  const unsigned short* Be = B + (size_t)expert * wstride;

  int tid = threadIdx.x;
  int lane = tid & 63, wid = tid >> 6;
  int wr = wid >> WRsh, wc = wid & ((1 << WRsh) - 1);
  int ncolbase = blockIdx.x * BN;

  // staging element offsets; source chunk pre-swizzled: sub = c ^ ((r>>1)&3)
  size_t aoff[2], boff[BSW];
#pragma unroll
  for (int l = 0; l < 2; ++l) {
    int g = l * 512 + tid;
    int r = g >> 2, cch = g & 3;
    int sub = cch ^ ((r >> 1) & 3);
    int gr = GATHER ? order[rowbase + r] : (rowbase + r);
    aoff[l] = (size_t)gr * lda + (size_t)(sub * 8);
  }
#pragma unroll
  for (int l = 0; l < BSW; ++l) {
    int g = l * 512 + tid;
    int r = g >> 2, cch = g & 3;
    int sub = cch ^ ((r >> 1) & 3);
    boff[l] = (size_t)(ncolbase + r) * K + (size_t)(sub * 8);
  }

  f32x4 acc[MF][4];
#pragma unroll
  for (int m = 0; m < MF; ++m)
#pragma unroll
    for (int n = 0; n < 4; ++n) acc[m][n] = f32x4{0.f, 0.f, 0.f, 0.f};

  const int NT = K >> 5;

  auto stage_a = [&](int kb, unsigned bo) {
#pragma unroll
    for (int l = 0; l < 2; ++l)
      gload16(A + aoff[l] + kb, &lds[bo + (size_t)(l * 512 + tid) * 8]);
  };
  auto stage_b = [&](int kb, unsigned bo) {
#pragma unroll
    for (int l = 0; l < BSW; ++l)
      gload16(Be + boff[l] + kb, &lds[bo + AE + (size_t)(l * 512 + tid) * 8]);
  };

  // prologue: stage tiles 0 and 1
  stage_a(0, 0);           stage_b(0, 0);
  stage_a(32, BUF);        stage_b(32, BUF);

  for (int t = 0; t < NT; ++t) {
    if (t + 1 < NT) {
      if (BN == 256) { asm volatile("s_waitcnt vmcnt(4)" ::: "memory"); }
      else           { asm volatile("s_waitcnt vmcnt(3)" ::: "memory"); }
    } else {
      asm volatile("s_waitcnt vmcnt(0)" ::: "memory");
    }
    asm volatile("s_waitcnt lgkmcnt(0)" ::: "memory");
    barrier_nodrain();   // tile t visible; write-target buffer free of readers

    const unsigned short* Ab = &lds[(unsigned)(t % 3) * BUF];
    const unsigned short* Bb = Ab + AE;
    const bool st = (t + 2 < NT);
    const int kb = (t + 2) << 5;
    const unsigned wo = (unsigned)((t + 2) % 3) * BUF;

    // B fragments (held across whole tile)
    bf16x8 bf[4];
#pragma unroll
    for (int n = 0; n < 4; ++n) {
      int row = wc * 64 + n * 16 + (lane & 15);
      int kc = (lane >> 4) ^ ((row >> 1) & 3);
      bf[n] = *(const bf16x8*)&Bb[row * 32 + kc * 8];
    }
    // A group 1 (m 0..3)
    bf16x8 af[4];
#pragma unroll
    for (int m = 0; m < 4; ++m) {
      int row = wr * WTM + m * 16 + (lane & 15);
      int kc = (lane >> 4) ^ ((row >> 1) & 3);
      af[m] = *(const bf16x8*)&Ab[row * 32 + kc * 8];
    }
    if (st) stage_a(kb, wo);
    if (MF == 4 && st) stage_b(kb, wo);
    __builtin_amdgcn_s_setprio(1);
#pragma unroll
    for (int m = 0; m < 4; ++m)
#pragma unroll
      for (int n = 0; n < 4; ++n)
        acc[m][n] = __builtin_amdgcn_mfma_f32_16x16x32_bf16(af[m], bf[n], acc[m][n], 0, 0, 0);
    __builtin_amdgcn_s_setprio(0);

    if (MF == 8) {
      // A group 2 (m 4..7)
#pragma unroll
      for (int m = 0; m < 4; ++m) {
        int row = wr * WTM + (m + 4) * 16 + (lane & 15);
        int kc = (lane >> 4) ^ ((row >> 1) & 3);
        af[m] = *(const bf16x8*)&Ab[row * 32 + kc * 8];
      }
      if (st) stage_b(kb, wo);
      __builtin_amdgcn_s_setprio(1);
#pragma unroll
      for (int m = 0; m < 4; ++m)
#pragma unroll
        for (int n = 0; n < 4; ++n)
          acc[(m + 4) % MF][n] = __builtin_amdgcn_mfma_f32_16x16x32_bf16(af[m], bf[n], acc[(m + 4) % MF][n], 0, 0, 0);
      __builtin_amdgcn_s_setprio(0);
    }
  }

  if (EPI == 0) {
    // interleaved pairs: n even = w1 fragment, n odd = w3 fragment; real cols = BN/2
#pragma unroll
    for (int m = 0; m < MF; ++m)
#pragma unroll
      for (int np = 0; np < 2; ++np) {
        int realcol = (ncolbase >> 1) + wc * 32 + np * 16 + (lane & 15);
        float bb1 = bias1[bstride * expert + realcol];
        float bb3 = bias3[bstride * expert + realcol];
#pragma unroll
        for (int j = 0; j < 4; ++j) {
          int row  = rowbase + wr * WTM + m * 16 + (lane >> 4) * 4 + j;
          float a1 = acc[m][2 * np][j] + bb1;
          float a3 = acc[m][2 * np + 1][j] + bb3;
          float hv = (a1 / (1.f + __expf(-a1))) * a3;   // silu(a1)*a3
          ((unsigned short*)outp)[(size_t)row * ldo + realcol] = f2b(hv);
        }
      }
  } else {
#pragma unroll
    for (int m = 0; m < MF; ++m)
#pragma unroll
      for (int n = 0; n < 4; ++n) {
        int col  = ncolbase + wc * 64 + n * 16 + (lane & 15);
        float bb = bias1[bstride * expert + col];
#pragma unroll
        for (int j = 0; j < 4; ++j) {
          int row = rowbase + wr * WTM + m * 16 + (lane >> 4) * 4 + j;
          float v = acc[m][n][j] + bb;
          if (EPI == 2)
            ((float*)outp)[(size_t)row * ldo + col] = v;
          else
            ((unsigned short*)outp)[(size_t)row * ldo + col] = f2b(v);
        }
      }
  }
}

// ---------------- combine: out += w0*y[p0] + w1*y[p1] ----------------
__global__ __launch_bounds__(256) void combine_kernel(
    float* __restrict__ out, const unsigned short* __restrict__ y,
    const int* __restrict__ pos, const float* __restrict__ tw) {
  size_t idx = (size_t)blockIdx.x * 256 + threadIdx.x;
  if (idx >= (size_t)T_TOK * DIMK) return;
  int t = (int)(idx >> 10);
  int d = (int)(idx & 1023);
  int p0 = pos[t * 2], p1 = pos[t * 2 + 1];
  float w0 = tw[t * 2], w1 = tw[t * 2 + 1];
  out[idx] += w0 * b2f(y[(size_t)p0 * DIMK + d]) + w1 * b2f(y[(size_t)p1 * DIMK + d]);
}

// ---------------- launch ----------------
extern "C" void kernel_launch(void* const* d_in, const int* in_sizes, int n_in,
                              void* d_out, int out_size, void* d_ws, size_t ws_size,
                              hipStream_t stream) {
  const float* x   = (const float*)d_in[0];
  const float* gw  = (const float*)d_in[1];
  const float* gb  = (const float*)d_in[2];
  const float* w1  = (const float*)d_in[3];
  const float* b1  = (const float*)d_in[4];
  const float* w3  = (const float*)d_in[5];
  const float* b3  = (const float*)d_in[6];
  const float* w2  = (const float*)d_in[7];
  const float* b2  = (const float*)d_in[8];
  const float* ws1 = (const float*)d_in[9];
  const float* bs1 = (const float*)d_in[10];
  const float* ws3 = (const float*)d_in[11];
  const float* bs3 = (const float*)d_in[12];
  const float* ws2 = (const float*)d_in[13];
  const float* bs2 = (const float*)d_in[14];
  float* out = (float*)d_out;
  (void)in_sizes; (void)n_in; (void)out_size; (void)ws_size;

  char* p = (char*)d_ws;
  auto alloc = [&](size_t bytes) -> void* {
    void* r = (void*)p;
    p += (bytes + 255) & ~(size_t)255;
    return r;
  };
  unsigned short* xb    = (unsigned short*)alloc((size_t)T_TOK * DIMK * 2);
  unsigned short* w13r  = (unsigned short*)alloc((size_t)NEXP * 2 * INTERK * DIMK * 2);
  unsigned short* w2b   = (unsigned short*)alloc((size_t)NEXP * DIMK * INTERK * 2);
  unsigned short* w13s  = (unsigned short*)alloc((size_t)2 * SINT * DIMK * 2);
  unsigned short* ws2b  = (unsigned short*)alloc((size_t)DIMK * SINT * 2);
  unsigned short* h     = (unsigned short*)alloc((size_t)CAP * INTERK * 2);
  unsigned short* yb    = (unsigned short*)alloc((size_t)CAP * DIMK * 2);
  unsigned short* hs    = (unsigned short*)alloc((size_t)T_TOK * SINT * 2);
  int*   top_i  = (int*)alloc((size_t)T_TOK * 2 * 4);
  float* top_w  = (float*)alloc((size_t)T_TOK * 2 * 4);
  int*   pos    = (int*)alloc((size_t)T_TOK * 2 * 4);
  int*   order  = (int*)alloc((size_t)CAP * 4);
  int*   poff   = (int*)alloc(64);

  auto cvt = [&](const float* src, unsigned short* dst, size_t n) {
    int n4 = (int)(n / 4);
    cvt_kernel<<<(n4 + 255) / 256, 256, 0, stream>>>((const float4*)src, dst, n4);
  };
  cvt(x,   xb,   (size_t)T_TOK * DIMK);
  cvt(w2,  w2b,  (size_t)NEXP * DIMK * INTERK);
  cvt(ws2, ws2b, (size_t)DIMK * SINT);

  {  // routed w1/w3 -> interleaved w13r
    int n = NEXP * INTERK * (DIMK / 4);
    cvt_w13_kernel<INTERK, DIMK / 4><<<(2 * n + 255) / 256, 256, 0, stream>>>(
        (const float4*)w1, (const float4*)w3, w13r, n);
  }
  {  // shared ws1/ws3 -> interleaved w13s
    int n = SINT * (DIMK / 4);
    cvt_w13_kernel<SINT, DIMK / 4><<<(2 * n + 255) / 256, 256, 0, stream>>>(
        (const float4*)ws1, (const float4*)ws3, w13s, n);
  }

  gate_kernel<<<T_TOK / 4, 256, 0, stream>>>(x, gw, gb, top_i, top_w);
  route_build_kernel<<<1, 512, 0, stream>>>(top_i, order, pos, poff);

  // routed expert pipeline (grid: x = N-slices, y = M row-tiles)
  gemm_kernel<true, true, 0, 256><<<dim3((2 * INTERK) / 256, RT256), 512, 0, stream>>>(
      xb, DIMK, order, poff, w13r, b1, b3,
      (size_t)2 * INTERK * DIMK, INTERK, DIMK, h, INTERK);
  gemm_kernel<true, false, 1, 128><<<dim3(DIMK / 128, RT256), 512, 0, stream>>>(
      h, INTERK, (const int*)nullptr, poff, w2b, b2, (const float*)nullptr,
      (size_t)DIMK * INTERK, DIMK, INTERK, (void*)yb, DIMK);

  // shared expert pipeline (writes z straight into d_out)
  gemm_kernel<false, false, 0, 256><<<dim3((2 * SINT) / 256, T_TOK / 256), 512, 0, stream>>>(
      xb, DIMK, (const int*)nullptr, (const int*)nullptr, w13s, bs1, bs3,
      (size_t)0, 0, DIMK, hs, SINT);
  gemm_kernel<false, false, 2, 128><<<dim3(DIMK / 128, T_TOK / 256), 512, 0, stream>>>(
      hs, SINT, (const int*)nullptr, (const int*)nullptr, ws2b, bs2, (const float*)nullptr,
      (size_t)0, 0, SINT, (void*)out, DIMK);

  // out += routed combine
  combine_kernel<<<(T_TOK * DIMK) / 256, 256, 0, stream>>>(out, yb, pos, top_w);
}

// Round 11
// 408.545 us; speedup vs baseline: 1.0062x; 1.0004x over previous
//
#include <hip/hip_runtime.h>
#include <stdint.h>
#include <stddef.h>

// ---------------- problem constants ----------------
#define T_TOK  8192        // B*S tokens
#define DIMK   1024        // model dim
#define INTERK 1024        // routed expert inter dim
#define NEXP   8
#define SINT   2048        // shared inter dim
#define CAP    18432       // 2*T + 8*256 padding capacity (slot rows, 256-aligned)
#define RT256  72          // CAP/256 row tiles (worst case)

typedef float  f32x4  __attribute__((ext_vector_type(4)));
typedef short  bf16x8 __attribute__((ext_vector_type(8)));

typedef __attribute__((address_space(1))) const unsigned int gas_u32;
typedef __attribute__((address_space(3))) unsigned int las_u32;

__device__ __forceinline__ void gload16(const void* g, void* l) {
  __builtin_amdgcn_global_load_lds((gas_u32*)g, (las_u32*)l, 16, 0, 0);
}

__device__ __forceinline__ unsigned short f2b(float f) {   // f32 -> bf16 RNE
  unsigned int u = __float_as_uint(f);
  u = (u + 0x7FFFu + ((u >> 16) & 1u)) >> 16;
  return (unsigned short)u;
}
__device__ __forceinline__ float b2f(unsigned short h) {
  return __uint_as_float(((unsigned int)h) << 16);
}

// raw barrier with compile-time memory fences (no vmcnt/lgkmcnt drain)
__device__ __forceinline__ void barrier_nodrain() {
  asm volatile("" ::: "memory");
  __builtin_amdgcn_s_barrier();
  asm volatile("" ::: "memory");
}

// ---------------- f32 -> bf16 convert (plain) ----------------
__global__ __launch_bounds__(256) void cvt_kernel(const float4* __restrict__ in,
                                                  unsigned short* __restrict__ out, int n4) {
  int i = blockIdx.x * 256 + threadIdx.x;
  if (i >= n4) return;
  float4 v = in[i];
  ushort4 o;
  o.x = f2b(v.x); o.y = f2b(v.y); o.z = f2b(v.z); o.w = f2b(v.w);
  *reinterpret_cast<ushort4*>(&out[(size_t)i * 4]) = o;
}

// ---------------- f32 -> bf16 convert, interleaving w1/w3 rows in 16-row groups ----
template <int ROWS_PER_E, int K4>
__global__ __launch_bounds__(256) void cvt_w13_kernel(
    const float4* __restrict__ w1, const float4* __restrict__ w3,
    unsigned short* __restrict__ out, int n /* = E*ROWS_PER_E*K4 */) {
  int idx = blockIdx.x * 256 + threadIdx.x;
  int is3 = idx >= n;
  int i = is3 ? idx - n : idx;
  if (i >= n) return;
  int r  = i / K4;
  int kc = i - r * K4;
  int e  = r / ROWS_PER_E;
  int rr = r - e * ROWS_PER_E;
  int g  = rr >> 4;
  size_t dst_r = (size_t)e * (2 * ROWS_PER_E) + g * 32 + (is3 ? 16 : 0) + (rr & 15);
  float4 v = (is3 ? w3 : w1)[i];
  ushort4 o;
  o.x = f2b(v.x); o.y = f2b(v.y); o.z = f2b(v.z); o.w = f2b(v.w);
  *reinterpret_cast<ushort4*>(&out[(dst_r * K4 + kc) * 4]) = o;
}

// ---------------- gate: f32 logits, softmax, top-2 (no atomics) ----------------
__global__ __launch_bounds__(256) void gate_kernel(
    const float* __restrict__ x, const float* __restrict__ gw, const float* __restrict__ gb,
    int* __restrict__ top_i, float* __restrict__ top_w) {
  int t    = blockIdx.x * 4 + (threadIdx.x >> 6);
  int lane = threadIdx.x & 63;
  const float* xr = x + (size_t)t * DIMK;
  float acc[NEXP];
#pragma unroll
  for (int e = 0; e < NEXP; ++e) acc[e] = 0.f;
  for (int i = lane; i < DIMK; i += 64) {
    float xv = xr[i];
#pragma unroll
    for (int e = 0; e < NEXP; ++e) acc[e] += xv * gw[e * DIMK + i];
  }
#pragma unroll
  for (int e = 0; e < NEXP; ++e) {
    float v = acc[e];
#pragma unroll
    for (int off = 32; off > 0; off >>= 1) v += __shfl_down(v, off, 64);
    acc[e] = v;
  }
  if (lane == 0) {
    float lg[NEXP];
#pragma unroll
    for (int e = 0; e < NEXP; ++e) lg[e] = acc[e] + gb[e];
    int i0 = 0;
#pragma unroll
    for (int e = 1; e < NEXP; ++e) if (lg[e] > lg[i0]) i0 = e;   // first index wins ties
    int i1 = (i0 == 0) ? 1 : 0;
#pragma unroll
    for (int e = 0; e < NEXP; ++e) if (e != i0 && lg[e] > lg[i1]) i1 = e;
    float mx = lg[i0], s = 0.f;
#pragma unroll
    for (int e = 0; e < NEXP; ++e) s += expf(lg[e] - mx);
    top_i[t * 2]     = i0;
    top_i[t * 2 + 1] = i1;
    top_w[t * 2]     = expf(lg[i0] - mx) / s;
    top_w[t * 2 + 1] = expf(lg[i1] - mx) / s;
  }
}

// ---------------- route_build: count + scan + slot-assign, deterministic ----------
__global__ __launch_bounds__(512) void route_build_kernel(
    const int* __restrict__ top_i, int* __restrict__ order, int* __restrict__ pos,
    int* __restrict__ poff_g) {
  __shared__ int cnt[NEXP][512];
  __shared__ int base[NEXP][512];
  __shared__ int totals[NEXP];
  __shared__ int poff_s[NEXP + 1];
  int tid = threadIdx.x;
  int lane = tid & 63, w = tid >> 6;
  const int t0 = tid * 16;

  int c[NEXP];
#pragma unroll
  for (int e = 0; e < NEXP; ++e) c[e] = 0;
  for (int j = 0; j < 16; ++j) {
    int e0 = top_i[(t0 + j) * 2];
    int e1 = top_i[(t0 + j) * 2 + 1];
#pragma unroll
    for (int e = 0; e < NEXP; ++e) c[e] += (e0 == e) + (e1 == e);
  }
#pragma unroll
  for (int e = 0; e < NEXP; ++e) cnt[e][tid] = c[e];
  __syncthreads();

  {
    int running = 0;
    for (int ch = 0; ch < 8; ++ch) {
      int v = cnt[w][ch * 64 + lane];
      int incl = v;
#pragma unroll
      for (int off = 1; off < 64; off <<= 1) {
        int u = __shfl_up(incl, off, 64);
        if (lane >= off) incl += u;
      }
      base[w][ch * 64 + lane] = running + incl - v;
      running += __shfl(incl, 63, 64);
    }
    if (lane == 0) totals[w] = running;
  }
  __syncthreads();

  if (tid == 0) {
    int off = 0;
#pragma unroll
    for (int e = 0; e < NEXP; ++e) {
      poff_s[e] = off;
      off += (totals[e] + 255) & ~255;
    }
    poff_s[NEXP] = off;
#pragma unroll
    for (int e = 0; e <= NEXP; ++e) poff_g[e] = poff_s[e];
  }
  __syncthreads();

  int cur[NEXP];
#pragma unroll
  for (int e = 0; e < NEXP; ++e) cur[e] = poff_s[e] + base[e][tid];
  for (int j = 0; j < 16; ++j) {
    int t = t0 + j;
#pragma unroll
    for (int k = 0; k < 2; ++k) {
      int ei = top_i[t * 2 + k];
      int p = 0;
#pragma unroll
      for (int e = 0; e < NEXP; ++e)
        if (ei == e) { p = cur[e]; cur[e] = p + 1; }
      order[p]       = t;
      pos[t * 2 + k] = p;
    }
  }

#pragma unroll
  for (int e = 0; e < NEXP; ++e) {
    int s = poff_s[e] + totals[e], en = poff_s[e + 1];
    for (int i = s + tid; i < en; i += 512) order[i] = 0;
  }
}

// ------- 256x256x64 GEMM, m201-style 4-phase interleave, 512 thr (8 waves 2Mx4N) ------
// 2 LDS buffers (128 KiB, 1 block/CU). Per K-tile:
//   vmcnt(0) [free: loads issued >=2 phases earlier] + barrier
//   P1: ds A(m0-3)8 + B(n0-1)4 | stage 4 A-loads(t+1) | bar | lgkm0 | prio1 16MFMA prio0 | bar
//   P2: ds B(n2-3)4            | stage 4 B-loads(t+1) | bar | lgkm0 | prio1 16MFMA prio0 | bar
//   P3: ds A(m4-7)8            |                      | bar | lgkm0 | prio1 16MFMA prio0 | bar
//   P4: prio1 16MFMA prio0  (pure-reg, reuses B n0-1)
// Swizzle: chunk = (kk*4 + lane>>4) ^ (row&7), involution mirrored in staging source.
// EPI 0: paired swiglu (interleaved w1/w3 B) -> bf16 H, real cols = 128/block
// EPI 1: bias -> bf16 out;  EPI 2: bias -> f32 out
#define AE256 16384   // 256*64 elems
#define BUF2  32768   // A+B elems per buffer
template <bool EXPERTS, bool GATHER, int EPI>
__global__ __launch_bounds__(512) void gemm256_kernel(
    const unsigned short* __restrict__ A, int lda,
    const int* __restrict__ order, const int* __restrict__ poff,
    const unsigned short* __restrict__ B,          // row-major [N][K], per-expert wstride
    const float* __restrict__ bias1, const float* __restrict__ bias3,
    size_t wstride, int bstride, int K,
    void* __restrict__ outp, int ldo) {
  __shared__ unsigned short lds[2 * BUF2];   // 128 KiB

  int rowbase = blockIdx.y * 256;
  int expert  = 0;
  if (EXPERTS) {
    if (rowbase >= poff[NEXP]) return;
    while (expert < NEXP - 1 && rowbase >= poff[expert + 1]) ++expert;
  }
  const unsigned short* Be = B + (size_t)expert * wstride;

  int tid = threadIdx.x;
  int lane = tid & 63, wid = tid >> 6;
  int wr = wid >> 2, wc = wid & 3;            // 2 x 4 wave grid: 128 rows x 64 cols each
  int ncolbase = blockIdx.x * 256;

  // staging element offsets; source chunk pre-swizzled: sub = (g&7) ^ (row&7)
  size_t aoff[4], boff[4];
#pragma unroll
  for (int l = 0; l < 4; ++l) {
    int g = l * 512 + tid;
    int r = g >> 3;
    int sub = (g & 7) ^ (r & 7);
    int gr = GATHER ? order[rowbase + r] : (rowbase + r);
    aoff[l] = (size_t)gr * lda + (size_t)(sub * 8);
    boff[l] = (size_t)(ncolbase + r) * K + (size_t)(sub * 8);
  }

  f32x4 acc[8][4];
#pragma unroll
  for (int m = 0; m < 8; ++m)
#pragma unroll
    for (int n = 0; n < 4; ++n) acc[m][n] = f32x4{0.f, 0.f, 0.f, 0.f};

  const int NT = K >> 6;

  auto stage_a = [&](int kb, unsigned bo) {
#pragma unroll
    for (int l = 0; l < 4; ++l)
      gload16(A + aoff[l] + kb, &lds[bo + (size_t)(l * 512 + tid) * 8]);
  };
  auto stage_b = [&](int kb, unsigned bo) {
#pragma unroll
    for (int l = 0; l < 4; ++l)
      gload16(Be + boff[l] + kb, &lds[bo + AE256 + (size_t)(l * 512 + tid) * 8]);
  };

  // prologue: stage tile 0 into buffer 0
  stage_a(0, 0);
  stage_b(0, 0);

  for (int t = 0; t < NT; ++t) {
    asm volatile("s_waitcnt vmcnt(0)" ::: "memory");  // tile t landed (issued >=2 phases ago)
    barrier_nodrain();                                // all waves' loads visible; write-buf free

    const unsigned bo = (unsigned)(t & 1) * BUF2;
    const unsigned short* Ab = &lds[bo];
    const unsigned short* Bb = &lds[bo + AE256];
    const bool st = (t + 1 < NT);
    const int kb = (t + 1) << 6;
    const unsigned wo = bo ^ BUF2;

    bf16x8 bf[4][2], af[4][2];

    // ===== P1: ds A m0-3 (8) + B n0-1 (4) | stage A | bar | 16 MFMA (m0-3 x n0-1) =====
#pragma unroll
    for (int m = 0; m < 4; ++m) {
      int row = wr * 128 + m * 16 + (lane & 15);
#pragma unroll
      for (int kk = 0; kk < 2; ++kk) {
        int kc = (kk * 4 + (lane >> 4)) ^ (row & 7);
        af[m][kk] = *(const bf16x8*)&Ab[row * 64 + kc * 8];
      }
    }
#pragma unroll
    for (int n = 0; n < 2; ++n) {
      int row = wc * 64 + n * 16 + (lane & 15);
#pragma unroll
      for (int kk = 0; kk < 2; ++kk) {
        int kc = (kk * 4 + (lane >> 4)) ^ (row & 7);
        bf[n][kk] = *(const bf16x8*)&Bb[row * 64 + kc * 8];
      }
    }
    if (st) stage_a(kb, wo);
    barrier_nodrain();
    asm volatile("s_waitcnt lgkmcnt(0)" ::: "memory");
    __builtin_amdgcn_s_setprio(1);
#pragma unroll
    for (int m = 0; m < 4; ++m)
#pragma unroll
      for (int n = 0; n < 2; ++n)
#pragma unroll
        for (int kk = 0; kk < 2; ++kk)
          acc[m][n] = __builtin_amdgcn_mfma_f32_16x16x32_bf16(af[m][kk], bf[n][kk], acc[m][n], 0, 0, 0);
    __builtin_amdgcn_s_setprio(0);
    barrier_nodrain();

    // ===== P2: ds B n2-3 (4) | stage B | bar | 16 MFMA (m0-3 x n2-3) =====
#pragma unroll
    for (int n = 2; n < 4; ++n) {
      int row = wc * 64 + n * 16 + (lane & 15);
#pragma unroll
      for (int kk = 0; kk < 2; ++kk) {
        int kc = (kk * 4 + (lane >> 4)) ^ (row & 7);
        bf[n][kk] = *(const bf16x8*)&Bb[row * 64 + kc * 8];
      }
    }
    if (st) stage_b(kb, wo);
    barrier_nodrain();
    asm volatile("s_waitcnt lgkmcnt(0)" ::: "memory");
    __builtin_amdgcn_s_setprio(1);
#pragma unroll
    for (int m = 0; m < 4; ++m)
#pragma unroll
      for (int n = 2; n < 4; ++n)
#pragma unroll
        for (int kk = 0; kk < 2; ++kk)
          acc[m][n] = __builtin_amdgcn_mfma_f32_16x16x32_bf16(af[m][kk], bf[n][kk], acc[m][n], 0, 0, 0);
    __builtin_amdgcn_s_setprio(0);
    barrier_nodrain();

    // ===== P3: ds A m4-7 (8) | bar | 16 MFMA (m4-7 x n2-3) =====
#pragma unroll
    for (int m = 0; m < 4; ++m) {
      int row = wr * 128 + (m + 4) * 16 + (lane & 15);
#pragma unroll
      for (int kk = 0; kk < 2; ++kk) {
        int kc = (kk * 4 + (lane >> 4)) ^ (row & 7);
        af[m][kk] = *(const bf16x8*)&Ab[row * 64 + kc * 8];
      }
    }
    barrier_nodrain();
    asm volatile("s_waitcnt lgkmcnt(0)" ::: "memory");
    __builtin_amdgcn_s_setprio(1);
#pragma unroll
    for (int m = 0; m < 4; ++m)
#pragma unroll
      for (int n = 2; n < 4; ++n)
#pragma unroll
        for (int kk = 0; kk < 2; ++kk)
          acc[m + 4][n] = __builtin_amdgcn_mfma_f32_16x16x32_bf16(af[m][kk], bf[n][kk], acc[m + 4][n], 0, 0, 0);
    __builtin_amdgcn_s_setprio(0);
    barrier_nodrain();

    // ===== P4: pure-reg 16 MFMA (m4-7 x n0-1) =====
    __builtin_amdgcn_s_setprio(1);
#pragma unroll
    for (int m = 0; m < 4; ++m)
#pragma unroll
      for (int n = 0; n < 2; ++n)
#pragma unroll
        for (int kk = 0; kk < 2; ++kk)
          acc[m + 4][n] = __builtin_amdgcn_mfma_f32_16x16x32_bf16(af[m][kk], bf[n][kk], acc[m + 4][n], 0, 0, 0);
    __builtin_amdgcn_s_setprio(0);
  }

  if (EPI == 0) {
    // interleaved pairs: n even = w1 fragment, n odd = w3 fragment; real cols = 128
#pragma unroll
    for (int m = 0; m < 8; ++m)
#pragma unroll
      for (int np = 0; np < 2; ++np) {
        int realcol = (ncolbase >> 1) + wc * 32 + np * 16 + (lane & 15);
        float bb1 = bias1[bstride * expert + realcol];
        float bb3 = bias3[bstride * expert + realcol];
#pragma unroll
        for (int j = 0; j < 4; ++j) {
          int row  = rowbase + wr * 128 + m * 16 + (lane >> 4) * 4 + j;
          float a1 = acc[m][2 * np][j] + bb1;
          float a3 = acc[m][2 * np + 1][j] + bb3;
          float hv = (a1 / (1.f + __expf(-a1))) * a3;   // silu(a1)*a3
          ((unsigned short*)outp)[(size_t)row * ldo + realcol] = f2b(hv);
        }
      }
  } else {
#pragma unroll
    for (int m = 0; m < 8; ++m)
#pragma unroll
      for (int n = 0; n < 4; ++n) {
        int col  = ncolbase + wc * 64 + n * 16 + (lane & 15);
        float bb = bias1[bstride * expert + col];
#pragma unroll
        for (int j = 0; j < 4; ++j) {
          int row = rowbase + wr * 128 + m * 16 + (lane >> 4) * 4 + j;
          float v = acc[m][n][j] + bb;
          if (EPI == 2)
            ((float*)outp)[(size_t)row * ldo + col] = v;
          else
            ((unsigned short*)outp)[(size_t)row * ldo + col] = f2b(v);
        }
      }
  }
}

// ---------------- combine: out += w0*y[p0] + w1*y[p1] ----------------
__global__ __launch_bounds__(256) void combine_kernel(
    float* __restrict__ out, const unsigned short* __restrict__ y,
    const int* __restrict__ pos, const float* __restrict__ tw) {
  size_t idx = (size_t)blockIdx.x * 256 + threadIdx.x;
  if (idx >= (size_t)T_TOK * DIMK) return;
  int t = (int)(idx >> 10);
  int d = (int)(idx & 1023);
  int p0 = pos[t * 2], p1 = pos[t * 2 + 1];
  float w0 = tw[t * 2], w1 = tw[t * 2 + 1];
  out[idx] += w0 * b2f(y[(size_t)p0 * DIMK + d]) + w1 * b2f(y[(size_t)p1 * DIMK + d]);
}

// ---------------- launch ----------------
extern "C" void kernel_launch(void* const* d_in, const int* in_sizes, int n_in,
                              void* d_out, int out_size, void* d_ws, size_t ws_size,
                              hipStream_t stream) {
  const float* x   = (const float*)d_in[0];
  const float* gw  = (const float*)d_in[1];
  const float* gb  = (const float*)d_in[2];
  const float* w1  = (const float*)d_in[3];
  const float* b1  = (const float*)d_in[4];
  const float* w3  = (const float*)d_in[5];
  const float* b3  = (const float*)d_in[6];
  const float* w2  = (const float*)d_in[7];
  const float* b2  = (const float*)d_in[8];
  const float* ws1 = (const float*)d_in[9];
  const float* bs1 = (const float*)d_in[10];
  const float* ws3 = (const float*)d_in[11];
  const float* bs3 = (const float*)d_in[12];
  const float* ws2 = (const float*)d_in[13];
  const float* bs2 = (const float*)d_in[14];
  float* out = (float*)d_out;
  (void)in_sizes; (void)n_in; (void)out_size; (void)ws_size;

  char* p = (char*)d_ws;
  auto alloc = [&](size_t bytes) -> void* {
    void* r = (void*)p;
    p += (bytes + 255) & ~(size_t)255;
    return r;
  };
  unsigned short* xb    = (unsigned short*)alloc((size_t)T_TOK * DIMK * 2);
  unsigned short* w13r  = (unsigned short*)alloc((size_t)NEXP * 2 * INTERK * DIMK * 2);
  unsigned short* w2b   = (unsigned short*)alloc((size_t)NEXP * DIMK * INTERK * 2);
  unsigned short* w13s  = (unsigned short*)alloc((size_t)2 * SINT * DIMK * 2);
  unsigned short* ws2b  = (unsigned short*)alloc((size_t)DIMK * SINT * 2);
  unsigned short* h     = (unsigned short*)alloc((size_t)CAP * INTERK * 2);
  unsigned short* yb    = (unsigned short*)alloc((size_t)CAP * DIMK * 2);
  unsigned short* hs    = (unsigned short*)alloc((size_t)T_TOK * SINT * 2);
  int*   top_i  = (int*)alloc((size_t)T_TOK * 2 * 4);
  float* top_w  = (float*)alloc((size_t)T_TOK * 2 * 4);
  int*   pos    = (int*)alloc((size_t)T_TOK * 2 * 4);
  int*   order  = (int*)alloc((size_t)CAP * 4);
  int*   poff   = (int*)alloc(64);

  auto cvt = [&](const float* src, unsigned short* dst, size_t n) {
    int n4 = (int)(n / 4);
    cvt_kernel<<<(n4 + 255) / 256, 256, 0, stream>>>((const float4*)src, dst, n4);
  };
  cvt(x,   xb,   (size_t)T_TOK * DIMK);
  cvt(w2,  w2b,  (size_t)NEXP * DIMK * INTERK);
  cvt(ws2, ws2b, (size_t)DIMK * SINT);

  {  // routed w1/w3 -> interleaved w13r
    int n = NEXP * INTERK * (DIMK / 4);
    cvt_w13_kernel<INTERK, DIMK / 4><<<(2 * n + 255) / 256, 256, 0, stream>>>(
        (const float4*)w1, (const float4*)w3, w13r, n);
  }
  {  // shared ws1/ws3 -> interleaved w13s
    int n = SINT * (DIMK / 4);
    cvt_w13_kernel<SINT, DIMK / 4><<<(2 * n + 255) / 256, 256, 0, stream>>>(
        (const float4*)ws1, (const float4*)ws3, w13s, n);
  }

  gate_kernel<<<T_TOK / 4, 256, 0, stream>>>(x, gw, gb, top_i, top_w);
  route_build_kernel<<<1, 512, 0, stream>>>(top_i, order, pos, poff);

  // routed expert pipeline (grid: x = N-slices, y = M row-tiles)
  gemm256_kernel<true, true, 0><<<dim3((2 * INTERK) / 256, RT256), 512, 0, stream>>>(
      xb, DIMK, order, poff, w13r, b1, b3,
      (size_t)2 * INTERK * DIMK, INTERK, DIMK, h, INTERK);
  gemm256_kernel<true, false, 1><<<dim3(DIMK / 256, RT256), 512, 0, stream>>>(
      h, INTERK, (const int*)nullptr, poff, w2b, b2, (const float*)nullptr,
      (size_t)DIMK * INTERK, DIMK, INTERK, (void*)yb, DIMK);

  // shared expert pipeline (writes z straight into d_out)
  gemm256_kernel<false, false, 0><<<dim3((2 * SINT) / 256, T_TOK / 256), 512, 0, stream>>>(
      xb, DIMK, (const int*)nullptr, (const int*)nullptr, w13s, bs1, bs3,
      (size_t)0, 0, DIMK, hs, SINT);
  gemm256_kernel<false, false, 2><<<dim3(DIMK / 256, T_TOK / 256), 512, 0, stream>>>(
      hs, SINT, (const int*)nullptr, (const int*)nullptr, ws2b, bs2, (const float*)nullptr,
      (size_t)0, 0, SINT, (void*)out, DIMK);

  // out += routed combine
  combine_kernel<<<(T_TOK * DIMK) / 256, 256, 0, stream>>>(out, yb, pos, top_w);
}

// Round 12
// 394.237 us; speedup vs baseline: 1.0427x; 1.0363x over previous
//
#include <hip/hip_runtime.h>
#include <stdint.h>
#include <stddef.h>

// ---------------- problem constants ----------------
#define T_TOK  8192        // B*S tokens
#define DIMK   1024        // model dim
#define INTERK 1024        // routed expert inter dim
#define NEXP   8
#define SINT   2048        // shared inter dim
#define CAP    18432       // 2*T + 8*256 padding capacity (slot rows, 256-aligned)
#define RT256  72          // CAP/256 row tiles (worst case)

#define NS1_R  16          // gemm1 routed N-slices (2*INTERK/128)
#define NS1_S  32          // gemm1 shared N-slices (2*SINT/128)
#define RT_S   32          // shared row tiles (T_TOK/256)
#define G1R    (NS1_R * RT256)          // 1152
#define G1     (G1R + NS1_S * RT_S)     // 2176
#define NS2    8           // gemm2 N-slices (DIMK/128)
#define G2R    (NS2 * RT256)            // 576
#define G2     (G2R + NS2 * RT_S)       // 832

typedef float  f32x4  __attribute__((ext_vector_type(4)));
typedef short  bf16x8 __attribute__((ext_vector_type(8)));

typedef __attribute__((address_space(1))) const unsigned int gas_u32;
typedef __attribute__((address_space(3))) unsigned int las_u32;

__device__ __forceinline__ void gload16(const void* g, void* l) {
  __builtin_amdgcn_global_load_lds((gas_u32*)g, (las_u32*)l, 16, 0, 0);
}

__device__ __forceinline__ unsigned short f2b(float f) {   // f32 -> bf16 RNE
  unsigned int u = __float_as_uint(f);
  u = (u + 0x7FFFu + ((u >> 16) & 1u)) >> 16;
  return (unsigned short)u;
}
__device__ __forceinline__ float b2f(unsigned short h) {
  return __uint_as_float(((unsigned int)h) << 16);
}

// raw barrier with compile-time memory fences (no vmcnt/lgkmcnt drain)
__device__ __forceinline__ void barrier_nodrain() {
  asm volatile("" ::: "memory");
  __builtin_amdgcn_s_barrier();
  asm volatile("" ::: "memory");
}

// ---------------- f32 -> bf16 convert (plain) ----------------
__global__ __launch_bounds__(256) void cvt_kernel(const float4* __restrict__ in,
                                                  unsigned short* __restrict__ out, int n4) {
  int i = blockIdx.x * 256 + threadIdx.x;
  if (i >= n4) return;
  float4 v = in[i];
  ushort4 o;
  o.x = f2b(v.x); o.y = f2b(v.y); o.z = f2b(v.z); o.w = f2b(v.w);
  *reinterpret_cast<ushort4*>(&out[(size_t)i * 4]) = o;
}

// ---------------- f32 -> bf16 convert, interleaving w1/w3 rows in 16-row groups ----
template <int ROWS_PER_E, int K4>
__global__ __launch_bounds__(256) void cvt_w13_kernel(
    const float4* __restrict__ w1, const float4* __restrict__ w3,
    unsigned short* __restrict__ out, int n /* = E*ROWS_PER_E*K4 */) {
  int idx = blockIdx.x * 256 + threadIdx.x;
  int is3 = idx >= n;
  int i = is3 ? idx - n : idx;
  if (i >= n) return;
  int r  = i / K4;
  int kc = i - r * K4;
  int e  = r / ROWS_PER_E;
  int rr = r - e * ROWS_PER_E;
  int g  = rr >> 4;
  size_t dst_r = (size_t)e * (2 * ROWS_PER_E) + g * 32 + (is3 ? 16 : 0) + (rr & 15);
  float4 v = (is3 ? w3 : w1)[i];
  ushort4 o;
  o.x = f2b(v.x); o.y = f2b(v.y); o.z = f2b(v.z); o.w = f2b(v.w);
  *reinterpret_cast<ushort4*>(&out[(dst_r * K4 + kc) * 4]) = o;
}

// ---------------- gate: f32 logits, softmax, top-2 (no atomics) ----------------
__global__ __launch_bounds__(256) void gate_kernel(
    const float* __restrict__ x, const float* __restrict__ gw, const float* __restrict__ gb,
    int* __restrict__ top_i, float* __restrict__ top_w) {
  int t    = blockIdx.x * 4 + (threadIdx.x >> 6);
  int lane = threadIdx.x & 63;
  const float* xr = x + (size_t)t * DIMK;
  float acc[NEXP];
#pragma unroll
  for (int e = 0; e < NEXP; ++e) acc[e] = 0.f;
  for (int i = lane; i < DIMK; i += 64) {
    float xv = xr[i];
#pragma unroll
    for (int e = 0; e < NEXP; ++e) acc[e] += xv * gw[e * DIMK + i];
  }
#pragma unroll
  for (int e = 0; e < NEXP; ++e) {
    float v = acc[e];
#pragma unroll
    for (int off = 32; off > 0; off >>= 1) v += __shfl_down(v, off, 64);
    acc[e] = v;
  }
  if (lane == 0) {
    float lg[NEXP];
#pragma unroll
    for (int e = 0; e < NEXP; ++e) lg[e] = acc[e] + gb[e];
    int i0 = 0;
#pragma unroll
    for (int e = 1; e < NEXP; ++e) if (lg[e] > lg[i0]) i0 = e;   // first index wins ties
    int i1 = (i0 == 0) ? 1 : 0;
#pragma unroll
    for (int e = 0; e < NEXP; ++e) if (e != i0 && lg[e] > lg[i1]) i1 = e;
    float mx = lg[i0], s = 0.f;
#pragma unroll
    for (int e = 0; e < NEXP; ++e) s += expf(lg[e] - mx);
    top_i[t * 2]     = i0;
    top_i[t * 2 + 1] = i1;
    top_w[t * 2]     = expf(lg[i0] - mx) / s;
    top_w[t * 2 + 1] = expf(lg[i1] - mx) / s;
  }
}

// ---------------- route_build: count + scan + slot-assign, deterministic ----------
__global__ __launch_bounds__(512) void route_build_kernel(
    const int* __restrict__ top_i, int* __restrict__ order, int* __restrict__ pos,
    int* __restrict__ poff_g) {
  __shared__ int cnt[NEXP][512];
  __shared__ int base[NEXP][512];
  __shared__ int totals[NEXP];
  __shared__ int poff_s[NEXP + 1];
  int tid = threadIdx.x;
  int lane = tid & 63, w = tid >> 6;
  const int t0 = tid * 16;

  int c[NEXP];
#pragma unroll
  for (int e = 0; e < NEXP; ++e) c[e] = 0;
  for (int j = 0; j < 16; ++j) {
    int e0 = top_i[(t0 + j) * 2];
    int e1 = top_i[(t0 + j) * 2 + 1];
#pragma unroll
    for (int e = 0; e < NEXP; ++e) c[e] += (e0 == e) + (e1 == e);
  }
#pragma unroll
  for (int e = 0; e < NEXP; ++e) cnt[e][tid] = c[e];
  __syncthreads();

  {
    int running = 0;
    for (int ch = 0; ch < 8; ++ch) {
      int v = cnt[w][ch * 64 + lane];
      int incl = v;
#pragma unroll
      for (int off = 1; off < 64; off <<= 1) {
        int u = __shfl_up(incl, off, 64);
        if (lane >= off) incl += u;
      }
      base[w][ch * 64 + lane] = running + incl - v;
      running += __shfl(incl, 63, 64);
    }
    if (lane == 0) totals[w] = running;
  }
  __syncthreads();

  if (tid == 0) {
    int off = 0;
#pragma unroll
    for (int e = 0; e < NEXP; ++e) {
      poff_s[e] = off;
      off += (totals[e] + 255) & ~255;
    }
    poff_s[NEXP] = off;
#pragma unroll
    for (int e = 0; e <= NEXP; ++e) poff_g[e] = poff_s[e];
  }
  __syncthreads();

  int cur[NEXP];
#pragma unroll
  for (int e = 0; e < NEXP; ++e) cur[e] = poff_s[e] + base[e][tid];
  for (int j = 0; j < 16; ++j) {
    int t = t0 + j;
#pragma unroll
    for (int k = 0; k < 2; ++k) {
      int ei = top_i[t * 2 + k];
      int p = 0;
#pragma unroll
      for (int e = 0; e < NEXP; ++e)
        if (ei == e) { p = cur[e]; cur[e] = p + 1; }
      order[p]       = t;
      pos[t * 2 + k] = p;
    }
  }

#pragma unroll
  for (int e = 0; e < NEXP; ++e) {
    int s = poff_s[e] + totals[e], en = poff_s[e + 1];
    for (int i = s + tid; i < en; i += 512) order[i] = 0;
  }
}

// ====== core round-8 GEMM body: BM=256, BN=128, BK=64, 512 thr (8 waves 4x2) ======
// Depth-2 prefetch, 3 LDS buffers (144 KB), counted vmcnt(6), one barrier per tile,
// loose compiler-scheduled body, setprio around MFMA clusters, XOR-swizzled LDS.
#define A_ELE   16384   // 256*64 elements per A buffer
#define B_ELE   8192    // 128*64 elements per B buffer
#define BUF_ELE (A_ELE + B_ELE)

// SWIGLU==true : EPI0 paired-swiglu epilogue -> bf16, real cols = 64/block-slice
// SWIGLU==false: bias epilogue, outf32 selects f32/bf16 store
template <bool SWIGLU>
__device__ __forceinline__ void gemm_core(
    const unsigned short* __restrict__ A, int lda, int K,
    const int* __restrict__ order, bool gather, int rowbase,
    const unsigned short* __restrict__ Be,
    const float* __restrict__ bias1e, const float* __restrict__ bias3e,
    int ncolbase, void* __restrict__ outp, int ldo, bool outf32,
    unsigned short* lds) {
  int tid = threadIdx.x;
  int lane = tid & 63, wid = tid >> 6;
  int wr = wid >> 1, wc = wid & 1;            // 4 x 2 wave grid: 64 rows x 64 cols each

  size_t aoff[4], boff[2];
#pragma unroll
  for (int l = 0; l < 4; ++l) {
    int g = l * 512 + tid;
    int r = g >> 3;
    int sub = (g & 7) ^ (r & 7);
    int gr = gather ? order[rowbase + r] : (rowbase + r);
    aoff[l] = (size_t)gr * lda + (size_t)(sub * 8);
  }
#pragma unroll
  for (int l = 0; l < 2; ++l) {
    int g = l * 512 + tid;
    int r = g >> 3;
    int sub = (g & 7) ^ (r & 7);
    boff[l] = (size_t)(ncolbase + r) * K + (size_t)(sub * 8);
  }

  f32x4 acc[4][4];
#pragma unroll
  for (int m = 0; m < 4; ++m)
#pragma unroll
    for (int n = 0; n < 4; ++n) acc[m][n] = f32x4{0.f, 0.f, 0.f, 0.f};

  const int NT = K >> 6;

  // prologue: stage tiles 0 and 1
#pragma unroll
  for (int l = 0; l < 4; ++l)
    gload16(A + aoff[l], &lds[(size_t)(l * 512 + tid) * 8]);
#pragma unroll
  for (int l = 0; l < 2; ++l)
    gload16(Be + boff[l], &lds[A_ELE + (size_t)(l * 512 + tid) * 8]);
#pragma unroll
  for (int l = 0; l < 4; ++l)
    gload16(A + aoff[l] + 64, &lds[BUF_ELE + (size_t)(l * 512 + tid) * 8]);
#pragma unroll
  for (int l = 0; l < 2; ++l)
    gload16(Be + boff[l] + 64, &lds[BUF_ELE + A_ELE + (size_t)(l * 512 + tid) * 8]);

  unsigned int off_r = 0, off_m = BUF_ELE, off_w = 2 * BUF_ELE;

  for (int t = 0; t < NT; ++t) {
    if (t + 1 < NT) {
      asm volatile("s_waitcnt vmcnt(6)" ::: "memory");
    } else {
      asm volatile("s_waitcnt vmcnt(0)" ::: "memory");
    }
    asm volatile("s_waitcnt lgkmcnt(0)" ::: "memory");
    barrier_nodrain();   // tile t visible; write-target buffer free of readers

    const unsigned short* Ab = &lds[off_r];
    const unsigned short* Bb = &lds[off_r + A_ELE];
    const bool st = (t + 2 < NT);
    const int kb = (t + 2) << 6;

    // ---- half kk=0: ds_reads, stage A, MFMA ----
    {
      bf16x8 a[4], b[4];
#pragma unroll
      for (int m = 0; m < 4; ++m) {
        int ra = wr * 64 + m * 16 + (lane & 15);
        int sa = ((lane >> 4)) ^ (ra & 7);
        a[m] = *(const bf16x8*)&Ab[ra * 64 + sa * 8];
      }
#pragma unroll
      for (int n = 0; n < 4; ++n) {
        int rb = wc * 64 + n * 16 + (lane & 15);
        int sb = ((lane >> 4)) ^ (rb & 7);
        b[n] = *(const bf16x8*)&Bb[rb * 64 + sb * 8];
      }
      if (st) {
#pragma unroll
        for (int l = 0; l < 4; ++l)
          gload16(A + aoff[l] + kb, &lds[off_w + (size_t)(l * 512 + tid) * 8]);
      }
      __builtin_amdgcn_s_setprio(1);
#pragma unroll
      for (int m = 0; m < 4; ++m)
#pragma unroll
        for (int n = 0; n < 4; ++n)
          acc[m][n] = __builtin_amdgcn_mfma_f32_16x16x32_bf16(a[m], b[n], acc[m][n], 0, 0, 0);
      __builtin_amdgcn_s_setprio(0);
    }
    // ---- half kk=1: ds_reads, stage B, MFMA ----
    {
      bf16x8 a[4], b[4];
#pragma unroll
      for (int m = 0; m < 4; ++m) {
        int ra = wr * 64 + m * 16 + (lane & 15);
        int sa = (4 + (lane >> 4)) ^ (ra & 7);
        a[m] = *(const bf16x8*)&Ab[ra * 64 + sa * 8];
      }
#pragma unroll
      for (int n = 0; n < 4; ++n) {
        int rb = wc * 64 + n * 16 + (lane & 15);
        int sb = (4 + (lane >> 4)) ^ (rb & 7);
        b[n] = *(const bf16x8*)&Bb[rb * 64 + sb * 8];
      }
      if (st) {
#pragma unroll
        for (int l = 0; l < 2; ++l)
          gload16(Be + boff[l] + kb, &lds[off_w + A_ELE + (size_t)(l * 512 + tid) * 8]);
      }
      __builtin_amdgcn_s_setprio(1);
#pragma unroll
      for (int m = 0; m < 4; ++m)
#pragma unroll
        for (int n = 0; n < 4; ++n)
          acc[m][n] = __builtin_amdgcn_mfma_f32_16x16x32_bf16(a[m], b[n], acc[m][n], 0, 0, 0);
      __builtin_amdgcn_s_setprio(0);
    }

    unsigned int tmp = off_r; off_r = off_m; off_m = off_w; off_w = tmp;
  }

  if (SWIGLU) {
#pragma unroll
    for (int m = 0; m < 4; ++m)
#pragma unroll
      for (int np = 0; np < 2; ++np) {
        int realcol = (ncolbase >> 1) + wc * 32 + np * 16 + (lane & 15);
        float bb1 = bias1e[realcol];
        float bb3 = bias3e[realcol];
#pragma unroll
        for (int j = 0; j < 4; ++j) {
          int row  = rowbase + wr * 64 + m * 16 + (lane >> 4) * 4 + j;
          float a1 = acc[m][2 * np][j] + bb1;
          float a3 = acc[m][2 * np + 1][j] + bb3;
          float hv = (a1 / (1.f + __expf(-a1))) * a3;   // silu(a1)*a3
          ((unsigned short*)outp)[(size_t)row * ldo + realcol] = f2b(hv);
        }
      }
  } else {
#pragma unroll
    for (int m = 0; m < 4; ++m)
#pragma unroll
      for (int n = 0; n < 4; ++n) {
        int col  = ncolbase + wc * 64 + n * 16 + (lane & 15);
        float bb = bias1e[col];
#pragma unroll
        for (int j = 0; j < 4; ++j) {
          int row = rowbase + wr * 64 + m * 16 + (lane >> 4) * 4 + j;
          float v = acc[m][n][j] + bb;
          if (outf32)
            ((float*)outp)[(size_t)row * ldo + col] = v;
          else
            ((unsigned short*)outp)[(size_t)row * ldo + col] = f2b(v);
        }
      }
  }
}

// ---------- merged gemm1 (routed + shared), one launch, XCD-swizzled 1D grid -------
__global__ __launch_bounds__(512) void gemm1m_kernel(
    const unsigned short* __restrict__ xb,
    const int* __restrict__ order, const int* __restrict__ poff,
    const unsigned short* __restrict__ w13r,
    const float* __restrict__ b1, const float* __restrict__ b3,
    const unsigned short* __restrict__ w13s,
    const float* __restrict__ bs1, const float* __restrict__ bs3,
    unsigned short* __restrict__ h, unsigned short* __restrict__ hs) {
  __shared__ unsigned short lds[3 * BUF_ELE];   // 144 KiB

  int raw = blockIdx.x;
  int id  = (raw & 7) * (G1 / 8) + (raw >> 3);   // bijective XCD swizzle (G1 % 8 == 0)

  if (id < G1R) {
    int by = id / NS1_R, bx = id - by * NS1_R;
    int rowbase = by * 256;
    if (rowbase >= poff[NEXP]) return;
    int expert = 0;
    while (expert < NEXP - 1 && rowbase >= poff[expert + 1]) ++expert;
    gemm_core<true>(xb, DIMK, DIMK, order, true, rowbase,
                    w13r + (size_t)expert * 2 * INTERK * DIMK,
                    b1 + expert * INTERK, b3 + expert * INTERK,
                    bx * 128, (void*)h, INTERK, false, lds);
  } else {
    int id2 = id - G1R;
    int by = id2 / NS1_S, bx = id2 - by * NS1_S;
    gemm_core<true>(xb, DIMK, DIMK, (const int*)nullptr, false, by * 256,
                    w13s, bs1, bs3,
                    bx * 128, (void*)hs, SINT, false, lds);
  }
}

// ---------- merged gemm2 (routed + shared), one launch, XCD-swizzled 1D grid -------
__global__ __launch_bounds__(512) void gemm2m_kernel(
    const unsigned short* __restrict__ h, const unsigned short* __restrict__ hs,
    const int* __restrict__ poff,
    const unsigned short* __restrict__ w2b, const float* __restrict__ b2,
    const unsigned short* __restrict__ ws2b, const float* __restrict__ bs2,
    unsigned short* __restrict__ yb, float* __restrict__ out) {
  __shared__ unsigned short lds[3 * BUF_ELE];   // 144 KiB

  int raw = blockIdx.x;
  int id  = (raw & 7) * (G2 / 8) + (raw >> 3);   // bijective XCD swizzle (G2 % 8 == 0)

  if (id < G2R) {
    int by = id / NS2, bx = id - by * NS2;
    int rowbase = by * 256;
    if (rowbase >= poff[NEXP]) return;
    int expert = 0;
    while (expert < NEXP - 1 && rowbase >= poff[expert + 1]) ++expert;
    gemm_core<false>(h, INTERK, INTERK, (const int*)nullptr, false, rowbase,
                     w2b + (size_t)expert * DIMK * INTERK,
                     b2 + expert * DIMK, (const float*)nullptr,
                     bx * 128, (void*)yb, DIMK, false, lds);
  } else {
    int id2 = id - G2R;
    int by = id2 / NS2, bx = id2 - by * NS2;
    gemm_core<false>(hs, SINT, SINT, (const int*)nullptr, false, by * 256,
                     ws2b, bs2, (const float*)nullptr,
                     bx * 128, (void*)out, DIMK, true, lds);
  }
}

// ---------------- combine: out += w0*y[p0] + w1*y[p1] ----------------
__global__ __launch_bounds__(256) void combine_kernel(
    float* __restrict__ out, const unsigned short* __restrict__ y,
    const int* __restrict__ pos, const float* __restrict__ tw) {
  size_t idx = (size_t)blockIdx.x * 256 + threadIdx.x;
  if (idx >= (size_t)T_TOK * DIMK) return;
  int t = (int)(idx >> 10);
  int d = (int)(idx & 1023);
  int p0 = pos[t * 2], p1 = pos[t * 2 + 1];
  float w0 = tw[t * 2], w1 = tw[t * 2 + 1];
  out[idx] += w0 * b2f(y[(size_t)p0 * DIMK + d]) + w1 * b2f(y[(size_t)p1 * DIMK + d]);
}

// ---------------- launch ----------------
extern "C" void kernel_launch(void* const* d_in, const int* in_sizes, int n_in,
                              void* d_out, int out_size, void* d_ws, size_t ws_size,
                              hipStream_t stream) {
  const float* x   = (const float*)d_in[0];
  const float* gw  = (const float*)d_in[1];
  const float* gb  = (const float*)d_in[2];
  const float* w1  = (const float*)d_in[3];
  const float* b1  = (const float*)d_in[4];
  const float* w3  = (const float*)d_in[5];
  const float* b3  = (const float*)d_in[6];
  const float* w2  = (const float*)d_in[7];
  const float* b2  = (const float*)d_in[8];
  const float* ws1 = (const float*)d_in[9];
  const float* bs1 = (const float*)d_in[10];
  const float* ws3 = (const float*)d_in[11];
  const float* bs3 = (const float*)d_in[12];
  const float* ws2 = (const float*)d_in[13];
  const float* bs2 = (const float*)d_in[14];
  float* out = (float*)d_out;
  (void)in_sizes; (void)n_in; (void)out_size; (void)ws_size;

  char* p = (char*)d_ws;
  auto alloc = [&](size_t bytes) -> void* {
    void* r = (void*)p;
    p += (bytes + 255) & ~(size_t)255;
    return r;
  };
  unsigned short* xb    = (unsigned short*)alloc((size_t)T_TOK * DIMK * 2);
  unsigned short* w13r  = (unsigned short*)alloc((size_t)NEXP * 2 * INTERK * DIMK * 2);
  unsigned short* w2b   = (unsigned short*)alloc((size_t)NEXP * DIMK * INTERK * 2);
  unsigned short* w13s  = (unsigned short*)alloc((size_t)2 * SINT * DIMK * 2);
  unsigned short* ws2b  = (unsigned short*)alloc((size_t)DIMK * SINT * 2);
  unsigned short* h     = (unsigned short*)alloc((size_t)CAP * INTERK * 2);
  unsigned short* yb    = (unsigned short*)alloc((size_t)CAP * DIMK * 2);
  unsigned short* hs    = (unsigned short*)alloc((size_t)T_TOK * SINT * 2);
  int*   top_i  = (int*)alloc((size_t)T_TOK * 2 * 4);
  float* top_w  = (float*)alloc((size_t)T_TOK * 2 * 4);
  int*   pos    = (int*)alloc((size_t)T_TOK * 2 * 4);
  int*   order  = (int*)alloc((size_t)CAP * 4);
  int*   poff   = (int*)alloc(64);

  auto cvt = [&](const float* src, unsigned short* dst, size_t n) {
    int n4 = (int)(n / 4);
    cvt_kernel<<<(n4 + 255) / 256, 256, 0, stream>>>((const float4*)src, dst, n4);
  };
  cvt(x,   xb,   (size_t)T_TOK * DIMK);
  cvt(w2,  w2b,  (size_t)NEXP * DIMK * INTERK);
  cvt(ws2, ws2b, (size_t)DIMK * SINT);

  {  // routed w1/w3 -> interleaved w13r
    int n = NEXP * INTERK * (DIMK / 4);
    cvt_w13_kernel<INTERK, DIMK / 4><<<(2 * n + 255) / 256, 256, 0, stream>>>(
        (const float4*)w1, (const float4*)w3, w13r, n);
  }
  {  // shared ws1/ws3 -> interleaved w13s
    int n = SINT * (DIMK / 4);
    cvt_w13_kernel<SINT, DIMK / 4><<<(2 * n + 255) / 256, 256, 0, stream>>>(
        (const float4*)ws1, (const float4*)ws3, w13s, n);
  }

  gate_kernel<<<T_TOK / 4, 256, 0, stream>>>(x, gw, gb, top_i, top_w);
  route_build_kernel<<<1, 512, 0, stream>>>(top_i, order, pos, poff);

  // merged gemm1 (routed + shared), then merged gemm2
  gemm1m_kernel<<<G1, 512, 0, stream>>>(xb, order, poff, w13r, b1, b3,
                                        w13s, bs1, bs3, h, hs);
  gemm2m_kernel<<<G2, 512, 0, stream>>>(h, hs, poff, w2b, b2, ws2b, bs2, yb, out);

  // out += routed combine
  combine_kernel<<<(T_TOK * DIMK) / 256, 256, 0, stream>>>(out, yb, pos, top_w);
}

// Round 13
// 375.609 us; speedup vs baseline: 1.0944x; 1.0496x over previous
//
#include <hip/hip_runtime.h>
#include <stdint.h>
#include <stddef.h>

// ---------------- problem constants ----------------
#define T_TOK  8192        // B*S tokens
#define DIMK   1024        // model dim
#define INTERK 1024        // routed expert inter dim
#define NEXP   8
#define SINT   2048        // shared inter dim
#define CAP    18432       // 2*T + 8*256 padding capacity (slot rows, 256-aligned)
#define RT256  72          // CAP/256 row tiles (worst case)

#define NS1_R  16          // gemm1 routed N-slices (2*INTERK/128)
#define NS1_S  32          // gemm1 shared N-slices (2*SINT/128)
#define RT_S   32          // shared row tiles (T_TOK/256)
#define G1R    (NS1_R * RT256)          // 1152
#define G1     (G1R + NS1_S * RT_S)     // 2176
#define NS2    8           // gemm2 N-slices (DIMK/128)
#define G2R    (NS2 * RT256)            // 576
#define G2     (G2R + NS2 * RT_S)       // 832

typedef float  f32x4  __attribute__((ext_vector_type(4)));
typedef short  bf16x8 __attribute__((ext_vector_type(8)));

typedef __attribute__((address_space(1))) const unsigned int gas_u32;
typedef __attribute__((address_space(3))) unsigned int las_u32;

__device__ __forceinline__ void gload16(const void* g, void* l) {
  __builtin_amdgcn_global_load_lds((gas_u32*)g, (las_u32*)l, 16, 0, 0);
}

__device__ __forceinline__ unsigned short f2b(float f) {   // f32 -> bf16 RNE
  unsigned int u = __float_as_uint(f);
  u = (u + 0x7FFFu + ((u >> 16) & 1u)) >> 16;
  return (unsigned short)u;
}
__device__ __forceinline__ float b2f(unsigned short h) {
  return __uint_as_float(((unsigned int)h) << 16);
}

// raw barrier with compile-time memory fences (no vmcnt/lgkmcnt drain)
__device__ __forceinline__ void barrier_nodrain() {
  asm volatile("" ::: "memory");
  __builtin_amdgcn_s_barrier();
  asm volatile("" ::: "memory");
}

// ---------------- merged weight converts: one launch, range-decoded ----------------
// ranges (float4 chunks): [0,2*N1)   w1/w3 -> w13r (interleaved 16-row groups)
//                         [.,+2*N2)  ws1/ws3 -> w13s
//                         [.,+N3)    w2 -> w2b (plain)
//                         [.,+N4)    ws2 -> ws2b (plain)
#define N1C 2097152   // NEXP*INTERK*(DIMK/4)
#define N2C 524288    // SINT*(DIMK/4)
#define N3C 2097152   // NEXP*DIMK*(INTERK/4)
#define N4C 524288    // DIMK*(SINT/4)
#define WCVT_BLOCKS ((2*N1C + 2*N2C + N3C + N4C) / 256)   // 30720
__global__ __launch_bounds__(256) void wcvt_all_kernel(
    const float4* __restrict__ w1, const float4* __restrict__ w3,
    const float4* __restrict__ ws1, const float4* __restrict__ ws3,
    const float4* __restrict__ w2, const float4* __restrict__ ws2,
    unsigned short* __restrict__ w13r, unsigned short* __restrict__ w13s,
    unsigned short* __restrict__ w2b, unsigned short* __restrict__ ws2b) {
  long long i = (long long)blockIdx.x * 256 + threadIdx.x;
  float4 v;
  unsigned short* dst;
  size_t didx;
  if (i < 2 * (long long)N1C) {
    int is3 = i >= N1C;
    int j = (int)(i - (long long)is3 * N1C);
    int r = j >> 8, kc = j & 255;
    int e = r >> 10, rr = r & 1023, g = rr >> 4;
    size_t dst_r = (size_t)e * (2 * INTERK) + g * 32 + (is3 ? 16 : 0) + (rr & 15);
    v = (is3 ? w3 : w1)[j];
    dst = w13r; didx = dst_r * 256 + kc;
  } else if ((i -= 2 * (long long)N1C) < 2 * (long long)N2C) {
    int is3 = i >= N2C;
    int j = (int)(i - (long long)is3 * N2C);
    int r = j >> 8, kc = j & 255;
    int g = r >> 4;
    size_t dst_r = (size_t)g * 32 + (is3 ? 16 : 0) + (r & 15);
    v = (is3 ? ws3 : ws1)[j];
    dst = w13s; didx = dst_r * 256 + kc;
  } else if ((i -= 2 * (long long)N2C) < (long long)N3C) {
    int j = (int)i;
    v = w2[j];
    dst = w2b; didx = (size_t)j;
  } else {
    int j = (int)(i - N3C);
    v = ws2[j];
    dst = ws2b; didx = (size_t)j;
  }
  ushort4 o;
  o.x = f2b(v.x); o.y = f2b(v.y); o.z = f2b(v.z); o.w = f2b(v.w);
  *reinterpret_cast<ushort4*>(&dst[didx * 4]) = o;
}

// ------- gate (f32 logits, softmax, top-2) FUSED with x -> bf16 convert -----------
// numerics of the gate dot identical to previous rounds (scalar stride-64 order).
__global__ __launch_bounds__(256) void gate_cvt_kernel(
    const float* __restrict__ x, const float* __restrict__ gw, const float* __restrict__ gb,
    int* __restrict__ top_i, float* __restrict__ top_w,
    unsigned short* __restrict__ xb) {
  int t    = blockIdx.x * 4 + (threadIdx.x >> 6);
  int lane = threadIdx.x & 63;
  const float* xr = x + (size_t)t * DIMK;
  unsigned short* xo = xb + (size_t)t * DIMK;
  float acc[NEXP];
#pragma unroll
  for (int e = 0; e < NEXP; ++e) acc[e] = 0.f;
  for (int i = lane; i < DIMK; i += 64) {
    float xv = xr[i];
    xo[i] = f2b(xv);
#pragma unroll
    for (int e = 0; e < NEXP; ++e) acc[e] += xv * gw[e * DIMK + i];
  }
#pragma unroll
  for (int e = 0; e < NEXP; ++e) {
    float v = acc[e];
#pragma unroll
    for (int off = 32; off > 0; off >>= 1) v += __shfl_down(v, off, 64);
    acc[e] = v;
  }
  if (lane == 0) {
    float lg[NEXP];
#pragma unroll
    for (int e = 0; e < NEXP; ++e) lg[e] = acc[e] + gb[e];
    int i0 = 0;
#pragma unroll
    for (int e = 1; e < NEXP; ++e) if (lg[e] > lg[i0]) i0 = e;   // first index wins ties
    int i1 = (i0 == 0) ? 1 : 0;
#pragma unroll
    for (int e = 0; e < NEXP; ++e) if (e != i0 && lg[e] > lg[i1]) i1 = e;
    float mx = lg[i0], s = 0.f;
#pragma unroll
    for (int e = 0; e < NEXP; ++e) s += expf(lg[e] - mx);
    top_i[t * 2]     = i0;
    top_i[t * 2 + 1] = i1;
    top_w[t * 2]     = expf(lg[i0] - mx) / s;
    top_w[t * 2 + 1] = expf(lg[i1] - mx) / s;
  }
}

// ---------------- route_build: count + scan + slot-assign, deterministic ----------
__global__ __launch_bounds__(512) void route_build_kernel(
    const int* __restrict__ top_i, int* __restrict__ order, int* __restrict__ pos,
    int* __restrict__ poff_g) {
  __shared__ int cnt[NEXP][512];
  __shared__ int base[NEXP][512];
  __shared__ int totals[NEXP];
  __shared__ int poff_s[NEXP + 1];
  int tid = threadIdx.x;
  int lane = tid & 63, w = tid >> 6;
  const int t0 = tid * 16;

  int c[NEXP];
#pragma unroll
  for (int e = 0; e < NEXP; ++e) c[e] = 0;
  for (int j = 0; j < 16; ++j) {
    int e0 = top_i[(t0 + j) * 2];
    int e1 = top_i[(t0 + j) * 2 + 1];
#pragma unroll
    for (int e = 0; e < NEXP; ++e) c[e] += (e0 == e) + (e1 == e);
  }
#pragma unroll
  for (int e = 0; e < NEXP; ++e) cnt[e][tid] = c[e];
  __syncthreads();

  {
    int running = 0;
    for (int ch = 0; ch < 8; ++ch) {
      int v = cnt[w][ch * 64 + lane];
      int incl = v;
#pragma unroll
      for (int off = 1; off < 64; off <<= 1) {
        int u = __shfl_up(incl, off, 64);
        if (lane >= off) incl += u;
      }
      base[w][ch * 64 + lane] = running + incl - v;
      running += __shfl(incl, 63, 64);
    }
    if (lane == 0) totals[w] = running;
  }
  __syncthreads();

  if (tid == 0) {
    int off = 0;
#pragma unroll
    for (int e = 0; e < NEXP; ++e) {
      poff_s[e] = off;
      off += (totals[e] + 255) & ~255;
    }
    poff_s[NEXP] = off;
#pragma unroll
    for (int e = 0; e <= NEXP; ++e) poff_g[e] = poff_s[e];
  }
  __syncthreads();

  int cur[NEXP];
#pragma unroll
  for (int e = 0; e < NEXP; ++e) cur[e] = poff_s[e] + base[e][tid];
  for (int j = 0; j < 16; ++j) {
    int t = t0 + j;
#pragma unroll
    for (int k = 0; k < 2; ++k) {
      int ei = top_i[t * 2 + k];
      int p = 0;
#pragma unroll
      for (int e = 0; e < NEXP; ++e)
        if (ei == e) { p = cur[e]; cur[e] = p + 1; }
      order[p]       = t;
      pos[t * 2 + k] = p;
    }
  }

#pragma unroll
  for (int e = 0; e < NEXP; ++e) {
    int s = poff_s[e] + totals[e], en = poff_s[e + 1];
    for (int i = s + tid; i < en; i += 512) order[i] = 0;
  }
}

// ====== core round-8 GEMM body: BM=256, BN=128, BK=64, 512 thr (8 waves 4x2) ======
// Depth-2 prefetch, 3 LDS buffers (144 KB), counted vmcnt(6), one barrier per tile,
// loose compiler-scheduled body, setprio around MFMA clusters, XOR-swizzled LDS.
#define A_ELE   16384   // 256*64 elements per A buffer
#define B_ELE   8192    // 128*64 elements per B buffer
#define BUF_ELE (A_ELE + B_ELE)

template <bool SWIGLU>
__device__ __forceinline__ void gemm_core(
    const unsigned short* __restrict__ A, int lda, int K,
    const int* __restrict__ order, bool gather, int rowbase,
    const unsigned short* __restrict__ Be,
    const float* __restrict__ bias1e, const float* __restrict__ bias3e,
    int ncolbase, void* __restrict__ outp, int ldo, bool outf32,
    unsigned short* lds) {
  int tid = threadIdx.x;
  int lane = tid & 63, wid = tid >> 6;
  int wr = wid >> 1, wc = wid & 1;            // 4 x 2 wave grid: 64 rows x 64 cols each

  size_t aoff[4], boff[2];
#pragma unroll
  for (int l = 0; l < 4; ++l) {
    int g = l * 512 + tid;
    int r = g >> 3;
    int sub = (g & 7) ^ (r & 7);
    int gr = gather ? order[rowbase + r] : (rowbase + r);
    aoff[l] = (size_t)gr * lda + (size_t)(sub * 8);
  }
#pragma unroll
  for (int l = 0; l < 2; ++l) {
    int g = l * 512 + tid;
    int r = g >> 3;
    int sub = (g & 7) ^ (r & 7);
    boff[l] = (size_t)(ncolbase + r) * K + (size_t)(sub * 8);
  }

  f32x4 acc[4][4];
#pragma unroll
  for (int m = 0; m < 4; ++m)
#pragma unroll
    for (int n = 0; n < 4; ++n) acc[m][n] = f32x4{0.f, 0.f, 0.f, 0.f};

  const int NT = K >> 6;

  // prologue: stage tiles 0 and 1
#pragma unroll
  for (int l = 0; l < 4; ++l)
    gload16(A + aoff[l], &lds[(size_t)(l * 512 + tid) * 8]);
#pragma unroll
  for (int l = 0; l < 2; ++l)
    gload16(Be + boff[l], &lds[A_ELE + (size_t)(l * 512 + tid) * 8]);
#pragma unroll
  for (int l = 0; l < 4; ++l)
    gload16(A + aoff[l] + 64, &lds[BUF_ELE + (size_t)(l * 512 + tid) * 8]);
#pragma unroll
  for (int l = 0; l < 2; ++l)
    gload16(Be + boff[l] + 64, &lds[BUF_ELE + A_ELE + (size_t)(l * 512 + tid) * 8]);

  unsigned int off_r = 0, off_m = BUF_ELE, off_w = 2 * BUF_ELE;

  for (int t = 0; t < NT; ++t) {
    if (t + 1 < NT) {
      asm volatile("s_waitcnt vmcnt(6)" ::: "memory");
    } else {
      asm volatile("s_waitcnt vmcnt(0)" ::: "memory");
    }
    asm volatile("s_waitcnt lgkmcnt(0)" ::: "memory");
    barrier_nodrain();   // tile t visible; write-target buffer free of readers

    const unsigned short* Ab = &lds[off_r];
    const unsigned short* Bb = &lds[off_r + A_ELE];
    const bool st = (t + 2 < NT);
    const int kb = (t + 2) << 6;

    // ---- half kk=0: ds_reads, stage A, MFMA ----
    {
      bf16x8 a[4], b[4];
#pragma unroll
      for (int m = 0; m < 4; ++m) {
        int ra = wr * 64 + m * 16 + (lane & 15);
        int sa = ((lane >> 4)) ^ (ra & 7);
        a[m] = *(const bf16x8*)&Ab[ra * 64 + sa * 8];
      }
#pragma unroll
      for (int n = 0; n < 4; ++n) {
        int rb = wc * 64 + n * 16 + (lane & 15);
        int sb = ((lane >> 4)) ^ (rb & 7);
        b[n] = *(const bf16x8*)&Bb[rb * 64 + sb * 8];
      }
      if (st) {
#pragma unroll
        for (int l = 0; l < 4; ++l)
          gload16(A + aoff[l] + kb, &lds[off_w + (size_t)(l * 512 + tid) * 8]);
      }
      __builtin_amdgcn_s_setprio(1);
#pragma unroll
      for (int m = 0; m < 4; ++m)
#pragma unroll
        for (int n = 0; n < 4; ++n)
          acc[m][n] = __builtin_amdgcn_mfma_f32_16x16x32_bf16(a[m], b[n], acc[m][n], 0, 0, 0);
      __builtin_amdgcn_s_setprio(0);
    }
    // ---- half kk=1: ds_reads, stage B, MFMA ----
    {
      bf16x8 a[4], b[4];
#pragma unroll
      for (int m = 0; m < 4; ++m) {
        int ra = wr * 64 + m * 16 + (lane & 15);
        int sa = (4 + (lane >> 4)) ^ (ra & 7);
        a[m] = *(const bf16x8*)&Ab[ra * 64 + sa * 8];
      }
#pragma unroll
      for (int n = 0; n < 4; ++n) {
        int rb = wc * 64 + n * 16 + (lane & 15);
        int sb = (4 + (lane >> 4)) ^ (rb & 7);
        b[n] = *(const bf16x8*)&Bb[rb * 64 + sb * 8];
      }
      if (st) {
#pragma unroll
        for (int l = 0; l < 2; ++l)
          gload16(Be + boff[l] + kb, &lds[off_w + A_ELE + (size_t)(l * 512 + tid) * 8]);
      }
      __builtin_amdgcn_s_setprio(1);
#pragma unroll
      for (int m = 0; m < 4; ++m)
#pragma unroll
        for (int n = 0; n < 4; ++n)
          acc[m][n] = __builtin_amdgcn_mfma_f32_16x16x32_bf16(a[m], b[n], acc[m][n], 0, 0, 0);
      __builtin_amdgcn_s_setprio(0);
    }

    unsigned int tmp = off_r; off_r = off_m; off_m = off_w; off_w = tmp;
  }

  if (SWIGLU) {
#pragma unroll
    for (int m = 0; m < 4; ++m)
#pragma unroll
      for (int np = 0; np < 2; ++np) {
        int realcol = (ncolbase >> 1) + wc * 32 + np * 16 + (lane & 15);
        float bb1 = bias1e[realcol];
        float bb3 = bias3e[realcol];
#pragma unroll
        for (int j = 0; j < 4; ++j) {
          int row  = rowbase + wr * 64 + m * 16 + (lane >> 4) * 4 + j;
          float a1 = acc[m][2 * np][j] + bb1;
          float a3 = acc[m][2 * np + 1][j] + bb3;
          float hv = (a1 / (1.f + __expf(-a1))) * a3;   // silu(a1)*a3
          ((unsigned short*)outp)[(size_t)row * ldo + realcol] = f2b(hv);
        }
      }
  } else {
#pragma unroll
    for (int m = 0; m < 4; ++m)
#pragma unroll
      for (int n = 0; n < 4; ++n) {
        int col  = ncolbase + wc * 64 + n * 16 + (lane & 15);
        float bb = bias1e[col];
#pragma unroll
        for (int j = 0; j < 4; ++j) {
          int row = rowbase + wr * 64 + m * 16 + (lane >> 4) * 4 + j;
          float v = acc[m][n][j] + bb;
          if (outf32)
            ((float*)outp)[(size_t)row * ldo + col] = v;
          else
            ((unsigned short*)outp)[(size_t)row * ldo + col] = f2b(v);
        }
      }
  }
}

// ---------- merged gemm1 (routed + shared), one launch, XCD-swizzled 1D grid -------
__global__ __launch_bounds__(512) void gemm1m_kernel(
    const unsigned short* __restrict__ xb,
    const int* __restrict__ order, const int* __restrict__ poff,
    const unsigned short* __restrict__ w13r,
    const float* __restrict__ b1, const float* __restrict__ b3,
    const unsigned short* __restrict__ w13s,
    const float* __restrict__ bs1, const float* __restrict__ bs3,
    unsigned short* __restrict__ h, unsigned short* __restrict__ hs) {
  __shared__ unsigned short lds[3 * BUF_ELE];   // 144 KiB

  int raw = blockIdx.x;
  int id  = (raw & 7) * (G1 / 8) + (raw >> 3);   // bijective XCD swizzle (G1 % 8 == 0)

  if (id < G1R) {
    int by = id / NS1_R, bx = id - by * NS1_R;
    int rowbase = by * 256;
    if (rowbase >= poff[NEXP]) return;
    int expert = 0;
    while (expert < NEXP - 1 && rowbase >= poff[expert + 1]) ++expert;
    gemm_core<true>(xb, DIMK, DIMK, order, true, rowbase,
                    w13r + (size_t)expert * 2 * INTERK * DIMK,
                    b1 + expert * INTERK, b3 + expert * INTERK,
                    bx * 128, (void*)h, INTERK, false, lds);
  } else {
    int id2 = id - G1R;
    int by = id2 / NS1_S, bx = id2 - by * NS1_S;
    gemm_core<true>(xb, DIMK, DIMK, (const int*)nullptr, false, by * 256,
                    w13s, bs1, bs3,
                    bx * 128, (void*)hs, SINT, false, lds);
  }
}

// ---------- merged gemm2 (routed + shared), one launch, XCD-swizzled 1D grid -------
__global__ __launch_bounds__(512) void gemm2m_kernel(
    const unsigned short* __restrict__ h, const unsigned short* __restrict__ hs,
    const int* __restrict__ poff,
    const unsigned short* __restrict__ w2b, const float* __restrict__ b2,
    const unsigned short* __restrict__ ws2b, const float* __restrict__ bs2,
    unsigned short* __restrict__ yb, float* __restrict__ out) {
  __shared__ unsigned short lds[3 * BUF_ELE];   // 144 KiB

  int raw = blockIdx.x;
  int id  = (raw & 7) * (G2 / 8) + (raw >> 3);   // bijective XCD swizzle (G2 % 8 == 0)

  if (id < G2R) {
    int by = id / NS2, bx = id - by * NS2;
    int rowbase = by * 256;
    if (rowbase >= poff[NEXP]) return;
    int expert = 0;
    while (expert < NEXP - 1 && rowbase >= poff[expert + 1]) ++expert;
    gemm_core<false>(h, INTERK, INTERK, (const int*)nullptr, false, rowbase,
                     w2b + (size_t)expert * DIMK * INTERK,
                     b2 + expert * DIMK, (const float*)nullptr,
                     bx * 128, (void*)yb, DIMK, false, lds);
  } else {
    int id2 = id - G2R;
    int by = id2 / NS2, bx = id2 - by * NS2;
    gemm_core<false>(hs, SINT, SINT, (const int*)nullptr, false, by * 256,
                     ws2b, bs2, (const float*)nullptr,
                     bx * 128, (void*)out, DIMK, true, lds);
  }
}

// ------------- combine (vectorized): out4 += w0*y4[p0] + w1*y4[p1] ----------------
// one block per token (256 threads x float4 = 1024 cols)
__global__ __launch_bounds__(256) void combine4_kernel(
    float* __restrict__ out, const unsigned short* __restrict__ y,
    const int* __restrict__ pos, const float* __restrict__ tw) {
  int t  = blockIdx.x;
  int d4 = threadIdx.x;
  int p0 = pos[t * 2], p1 = pos[t * 2 + 1];
  float w0 = tw[t * 2], w1 = tw[t * 2 + 1];
  ushort4 y0 = ((const ushort4*)(y + (size_t)p0 * DIMK))[d4];
  ushort4 y1 = ((const ushort4*)(y + (size_t)p1 * DIMK))[d4];
  float4* o4 = (float4*)(out + (size_t)t * DIMK);
  float4 o = o4[d4];
  o.x += w0 * b2f(y0.x) + w1 * b2f(y1.x);
  o.y += w0 * b2f(y0.y) + w1 * b2f(y1.y);
  o.z += w0 * b2f(y0.z) + w1 * b2f(y1.z);
  o.w += w0 * b2f(y0.w) + w1 * b2f(y1.w);
  o4[d4] = o;
}

// ---------------- launch ----------------
extern "C" void kernel_launch(void* const* d_in, const int* in_sizes, int n_in,
                              void* d_out, int out_size, void* d_ws, size_t ws_size,
                              hipStream_t stream) {
  const float* x   = (const float*)d_in[0];
  const float* gw  = (const float*)d_in[1];
  const float* gb  = (const float*)d_in[2];
  const float* w1  = (const float*)d_in[3];
  const float* b1  = (const float*)d_in[4];
  const float* w3  = (const float*)d_in[5];
  const float* b3  = (const float*)d_in[6];
  const float* w2  = (const float*)d_in[7];
  const float* b2  = (const float*)d_in[8];
  const float* ws1 = (const float*)d_in[9];
  const float* bs1 = (const float*)d_in[10];
  const float* ws3 = (const float*)d_in[11];
  const float* bs3 = (const float*)d_in[12];
  const float* ws2 = (const float*)d_in[13];
  const float* bs2 = (const float*)d_in[14];
  float* out = (float*)d_out;
  (void)in_sizes; (void)n_in; (void)out_size; (void)ws_size;

  char* p = (char*)d_ws;
  auto alloc = [&](size_t bytes) -> void* {
    void* r = (void*)p;
    p += (bytes + 255) & ~(size_t)255;
    return r;
  };
  unsigned short* xb    = (unsigned short*)alloc((size_t)T_TOK * DIMK * 2);
  unsigned short* w13r  = (unsigned short*)alloc((size_t)NEXP * 2 * INTERK * DIMK * 2);
  unsigned short* w2b   = (unsigned short*)alloc((size_t)NEXP * DIMK * INTERK * 2);
  unsigned short* w13s  = (unsigned short*)alloc((size_t)2 * SINT * DIMK * 2);
  unsigned short* ws2b  = (unsigned short*)alloc((size_t)DIMK * SINT * 2);
  unsigned short* h     = (unsigned short*)alloc((size_t)CAP * INTERK * 2);
  unsigned short* yb    = (unsigned short*)alloc((size_t)CAP * DIMK * 2);
  unsigned short* hs    = (unsigned short*)alloc((size_t)T_TOK * SINT * 2);
  int*   top_i  = (int*)alloc((size_t)T_TOK * 2 * 4);
  float* top_w  = (float*)alloc((size_t)T_TOK * 2 * 4);
  int*   pos    = (int*)alloc((size_t)T_TOK * 2 * 4);
  int*   order  = (int*)alloc((size_t)CAP * 4);
  int*   poff   = (int*)alloc(64);

  // gate + x convert fused; routing build; merged weight converts
  gate_cvt_kernel<<<T_TOK / 4, 256, 0, stream>>>(x, gw, gb, top_i, top_w, xb);
  route_build_kernel<<<1, 512, 0, stream>>>(top_i, order, pos, poff);
  wcvt_all_kernel<<<WCVT_BLOCKS, 256, 0, stream>>>(
      (const float4*)w1, (const float4*)w3, (const float4*)ws1, (const float4*)ws3,
      (const float4*)w2, (const float4*)ws2, w13r, w13s, w2b, ws2b);

  // merged gemm1 (routed + shared), then merged gemm2
  gemm1m_kernel<<<G1, 512, 0, stream>>>(xb, order, poff, w13r, b1, b3,
                                        w13s, bs1, bs3, h, hs);
  gemm2m_kernel<<<G2, 512, 0, stream>>>(h, hs, poff, w2b, b2, ws2b, bs2, yb, out);

  // out += routed combine (vectorized)
  combine4_kernel<<<T_TOK, 256, 0, stream>>>(out, yb, pos, top_w);
}